// Round 5
// baseline (565.917 us; speedup 1.0000x reference)
//
#include <hip/hip_runtime.h>
#include <math.h>

#define DIMC 96
#define DINC 192
#define NSTC 16
#define DTRC 6
#define KDIR 4
#define BB   2
#define HH   56
#define WWD  56
#define LL   3136
#define NPIX (BB*LL)           // 6272
#define EPSF 1e-5f
#define NCHAIN (BB*KDIR*DINC)  // 1536
#define NCOLS 152              // 4*38
#define LC2  56                // chunk length in fused scan
#define NC2  56                // chunks per chain (56*56 = 3136)

// ---------- workspace layout (float offsets) ----------
#define OFF_XN     0u          // 602112  H3 later
#define OFF_XCRAW  602112u     // 1204224 xc pre-conv NCHW; y_t after scan
#define OFF_ZS     1806336u    // 1204224 silu(z) (B,L,192)
#define OFF_XCONV  3010560u    // 1204224 silu(conv(xc)) NCHW
#define OFF_DTS    4214784u    // 150528  dts (B,K,L,6)
#define OFF_BC     4365312u    // 802816  (B,K,L,16,{B,C})
#define OFF_XCONVT 5168128u    // 1204224 transposed xconv (dead after scan)
#define OFF_YS     14801920u   // 4816896 ys (B,K,192,L)
#define OFF_YT     OFF_XCRAW
#define OFF_VL     OFF_XCONVT              // 602112 (written after xconvT dead)
#define OFF_H1     (OFF_XCONVT + 1300000u) // 150528 (after xconvT dead)
#define OFF_H2     (OFF_XCONVT + 1500000u) // 150528
#define OFF_H3     OFF_XN
#define OFF_POOL   (OFF_XCONVT + 1700000u)
#define OFF_SEW    (OFF_XCONVT + 1700448u)

__device__ __forceinline__ float siluf(float x) { return x / (1.f + __expf(-x)); }
__device__ __forceinline__ float softplusf(float x) {
    return fmaxf(x, 0.f) + log1pf(__expf(-fabsf(x)));
}

// ---------- 1. fused LN1 + in_proj GEMM. grid (98,4) x 256 ----------
__global__ __launch_bounds__(256) void gemm1_k(const float* __restrict__ x,
                                               const float* __restrict__ g,
                                               const float* __restrict__ bt,
                                               const float* __restrict__ W,
                                               float* __restrict__ xcr,
                                               float* __restrict__ zs) {
    __shared__ float xT[64 * 97];
    __shared__ float wT[96 * 100];
    __shared__ float mA[64], iA[64];
    int row0 = blockIdx.x * 64;
    int b = row0 / LL, pos0 = row0 % LL;
    int c0 = blockIdx.y * 96;
    for (int f = threadIdx.x; f < 96 * 16; f += 256) {
        int ch = f >> 4, po = (f & 15) * 4;
        float4 v = *(const float4*)&x[((size_t)b * DIMC + ch) * LL + pos0 + po];
        xT[(po + 0) * 97 + ch] = v.x; xT[(po + 1) * 97 + ch] = v.y;
        xT[(po + 2) * 97 + ch] = v.z; xT[(po + 3) * 97 + ch] = v.w;
    }
    for (int f = threadIdx.x; f < 96 * 24; f += 256) {
        int r = f / 24, kq = (f % 24) * 4;
        *(float4*)&wT[r * 100 + kq] = *(const float4*)&W[(size_t)(c0 + r) * DIMC + kq];
    }
    __syncthreads();
    if (threadIdx.x < 64) {
        float s = 0.f, q = 0.f;
        const float* xr = &xT[threadIdx.x * 97];
        for (int c = 0; c < 96; ++c) { float v = xr[c]; s += v; q = fmaf(v, v, q); }
        float m = s * (1.f / 96.f);
        mA[threadIdx.x] = m;
        iA[threadIdx.x] = rsqrtf(q * (1.f / 96.f) - m * m + EPSF);
    }
    __syncthreads();
    for (int e = threadIdx.x; e < 64 * 96; e += 256) {
        int row = e / 96, col = e - row * 96;
        float v = xT[row * 97 + col];
        xT[row * 97 + col] = (v - mA[row]) * iA[row] * g[col] + bt[col];
    }
    __syncthreads();
    int tc = threadIdx.x & 15, tr = threadIdx.x >> 4;
    float acc[4][6] = {};
    for (int k = 0; k < 96; ++k) {
        float xv[4], wv[6];
#pragma unroll
        for (int i = 0; i < 4; ++i) xv[i] = xT[(4 * tr + i) * 97 + k];
#pragma unroll
        for (int j = 0; j < 6; ++j) wv[j] = wT[(tc + 16 * j) * 100 + k];
#pragma unroll
        for (int i = 0; i < 4; ++i)
#pragma unroll
            for (int j = 0; j < 6; ++j) acc[i][j] = fmaf(xv[i], wv[j], acc[i][j]);
    }
    int pos = pos0 + 4 * tr;
    if (c0 < DINC) {
#pragma unroll
        for (int j = 0; j < 6; ++j) {
            int col = c0 + tc + 16 * j;
            float4 v = make_float4(acc[0][j], acc[1][j], acc[2][j], acc[3][j]);
            *(float4*)&xcr[((size_t)b * DINC + col) * LL + pos] = v;
        }
    } else {
#pragma unroll
        for (int i = 0; i < 4; ++i)
#pragma unroll
            for (int j = 0; j < 6; ++j) {
                int zc = c0 - DINC + tc + 16 * j;
                zs[(size_t)(row0 + 4 * tr + i) * DINC + zc] = siluf(acc[i][j]);
            }
    }
}

// ---------- 2. depthwise 3x3 conv + silu, emits xconv AND xconvT ----------
__global__ __launch_bounds__(448) void dwconvt_k(const float* __restrict__ xcr,
                                                 const float* __restrict__ cw,
                                                 const float* __restrict__ cb,
                                                 float* __restrict__ xconv,
                                                 float* __restrict__ xconvT) {
    __shared__ float P[56 * 57];
    __shared__ float T[56 * 57];
    int bd = blockIdx.x;  // b*192+d
    int d = bd % DINC;
    size_t base = (size_t)bd * LL;
    for (int t = threadIdx.x; t < LL; t += 448)
        P[(t / 56) * 57 + (t % 56)] = xcr[base + t];
    float wk[9];
#pragma unroll
    for (int q = 0; q < 9; ++q) wk[q] = cw[d * 9 + q];
    float bias = cb[d];
    __syncthreads();
    for (int t = threadIdx.x; t < LL; t += 448) {
        int h = t / 56, w = t % 56;
        float acc = bias;
#pragma unroll
        for (int ky = 0; ky < 3; ++ky) {
            int y = h + ky - 1;
            if ((unsigned)y >= 56u) continue;
#pragma unroll
            for (int kx = 0; kx < 3; ++kx) {
                int xq = w + kx - 1;
                if ((unsigned)xq >= 56u) continue;
                acc = fmaf(wk[ky * 3 + kx], P[y * 57 + xq], acc);
            }
        }
        float v = siluf(acc);
        xconv[base + t] = v;
        T[w * 57 + h] = v;
    }
    __syncthreads();
    for (int t = threadIdx.x; t < LL; t += 448)
        xconvT[base + t] = T[(t / 56) * 57 + (t % 56)];
}

// ---------- 3. x_proj LDS-tiled GEMM -> scattered dts/bc. grid 98 x 256 ----------
__global__ __launch_bounds__(256) void gemmx_k(const float* __restrict__ xconv,
                                               const float* __restrict__ xpw,
                                               float* __restrict__ dts,
                                               float* __restrict__ bc) {
    __shared__ float xT[64 * 49];
    __shared__ float wT[NCOLS * 52];
    int row0 = blockIdx.x * 64;
    int b = row0 / LL, pos0 = row0 % LL;
    int tc = threadIdx.x & 15, tr = threadIdx.x >> 4;
    float acc[4][10] = {};
    for (int kc = 0; kc < 4; ++kc) {
        if (kc) __syncthreads();
        for (int f = threadIdx.x; f < 48 * 16; f += 256) {
            int dd = f >> 4, po = (f & 15) * 4;
            float4 v = *(const float4*)&xconv[((size_t)b * DINC + kc * 48 + dd) * LL + pos0 + po];
            xT[(po + 0) * 49 + dd] = v.x; xT[(po + 1) * 49 + dd] = v.y;
            xT[(po + 2) * 49 + dd] = v.z; xT[(po + 3) * 49 + dd] = v.w;
        }
        for (int f = threadIdx.x; f < NCOLS * 12; f += 256) {
            int r = f / 12, kq = (f % 12) * 4;
            *(float4*)&wT[r * 52 + kq] = *(const float4*)&xpw[(size_t)r * DINC + kc * 48 + kq];
        }
        __syncthreads();
        for (int k = 0; k < 48; ++k) {
            float xv[4], wv[10];
#pragma unroll
            for (int i = 0; i < 4; ++i) xv[i] = xT[(4 * tr + i) * 49 + k];
#pragma unroll
            for (int j = 0; j < 10; ++j) {
                int c = tc + 16 * j;
                wv[j] = (c < NCOLS) ? wT[c * 52 + k] : 0.f;
            }
#pragma unroll
            for (int i = 0; i < 4; ++i)
#pragma unroll
                for (int j = 0; j < 10; ++j) acc[i][j] = fmaf(xv[i], wv[j], acc[i][j]);
        }
    }
#pragma unroll
    for (int i = 0; i < 4; ++i) {
        int pos = pos0 + 4 * tr + i;
        int h = pos / 56, w = pos - 56 * h;
        int lt = w * 56 + h;
#pragma unroll
        for (int j = 0; j < 10; ++j) {
            int c = tc + 16 * j;
            if (c >= NCOLS) continue;
            int k = c / 38, idx = c - 38 * k;
            int l = (k == 0) ? pos : (k == 1) ? lt : (k == 2) ? (LL - 1 - pos) : (LL - 1 - lt);
            size_t rb = (size_t)(b * KDIR + k) * LL + l;
            float v = acc[i][j];
            if (idx < DTRC)    dts[rb * DTRC + idx] = v;
            else if (idx < 22) bc[(rb * NSTC + idx - 6) * 2] = v;
            else               bc[(rb * NSTC + idx - 22) * 2 + 1] = v;
        }
    }
}

// ---------- 4. fused selective scan: one block per chain, 3 phases in LDS ----------
__global__ __launch_bounds__(896) void scan_k(const float* __restrict__ dts,
                                              const float2* __restrict__ bc2,
                                              const float* __restrict__ alog,
                                              const float* __restrict__ dtw,
                                              const float* __restrict__ dtb,
                                              const float* __restrict__ xconv,
                                              const float* __restrict__ xconvT,
                                              float* __restrict__ ys) {
    __shared__ float sdel[LL];       // delta per l
    __shared__ float sdx[LL];        // delta*x per l
    __shared__ float sy[LL];         // y output plane
    __shared__ float aggA[NC2 * 16];
    __shared__ float aggB[NC2 * 16];
    __shared__ float ssum[NC2];
    int chain = blockIdx.x;          // (b*4+k)*192+d
    int d = chain % DINC, k = (chain / DINC) % KDIR, b = chain / (DINC * KDIR);
    int g = threadIdx.x >> 4, lane = threadIdx.x & 15;
    float An = -__expf(alog[(size_t)(chain % (KDIR * DINC)) * NSTC + lane]);
    float wr[DTRC];
#pragma unroll
    for (int r = 0; r < DTRC; ++r) wr[r] = dtw[((size_t)k * DINC + d) * DTRC + r];
    float bias = dtb[k * DINC + d];
    size_t bk = (size_t)(b * KDIR + k);
    int l0 = g * LC2;
    const float* dtp = dts + (bk * LL + l0) * DTRC;
    const float2* bcp = bc2 + (bk * LL + l0) * NSTC + lane;
    size_t bd = ((size_t)b * DINC + d) * LL;
    const float* xsrc = (k & 1) ? (xconvT + bd) : (xconv + bd);
    bool rev = (k >= 2);
    // ---- phase A: chunk-local scan, write {delta, delta*x} to LDS ----
    float h = 0.f, sd = 0.f;
    for (int s = 0; s < LC2; ++s) {
        int l = l0 + s;
        float acc = bias;
#pragma unroll
        for (int r = 0; r < DTRC; ++r) acc = fmaf(wr[r], dtp[s * DTRC + r], acc);
        float dv = softplusf(acc);
        float xv = xsrc[rev ? (LL - 1 - l) : l];
        float dx = dv * xv;
        if (lane == 0) { sdel[l] = dv; sdx[l] = dx; }
        float2 bcv = bcp[s * NSTC];
        h = fmaf(__expf(dv * An), h, dx * bcv.x);
        sd += dv;
    }
    if (lane == 0) ssum[g] = sd;
    __syncthreads();
    // ---- phase B: Hillis-Steele over chunk aggregates ----
    float A = __expf(An * ssum[g]);
    float Bv = h;
    int idx = g * 16 + lane;
    aggA[idx] = A; aggB[idx] = Bv;
    __syncthreads();
    for (int dd = 1; dd < NC2; dd <<= 1) {
        float pA = 1.f, pB = 0.f;
        if (g >= dd) { pA = aggA[idx - dd * 16]; pB = aggB[idx - dd * 16]; }
        __syncthreads();
        if (g >= dd) { Bv = fmaf(A, pB, Bv); A *= pA; aggA[idx] = A; aggB[idx] = Bv; }
        __syncthreads();
    }
    // ---- phase C: re-scan with h0 = prefix, emit y ----
    h = (g == 0) ? 0.f : aggB[idx - 16];
#pragma unroll 4
    for (int s = 0; s < LC2; ++s) {
        int l = l0 + s;
        float2 bcv = bcp[s * NSTC];
        h = fmaf(__expf(sdel[l] * An), h, sdx[l] * bcv.x);
        float p = h * bcv.y;
        p += __shfl_xor(p, 1, 16);
        p += __shfl_xor(p, 2, 16);
        p += __shfl_xor(p, 4, 16);
        p += __shfl_xor(p, 8, 16);
        if (lane == 0) sy[l] = p;
    }
    __syncthreads();
    float* yo = ys + (size_t)chain * LL;
    if (threadIdx.x < LL / 4) {
        *(float4*)&yo[threadIdx.x * 4] = *(const float4*)&sy[threadIdx.x * 4];
    }
}

// ---------- 5. combine 4 directions (+ D*x) with in-LDS transpose ----------
__global__ __launch_bounds__(448) void combine_k(const float* __restrict__ ys,
                                                 const float* __restrict__ xconv,
                                                 const float* __restrict__ dsv,
                                                 float* __restrict__ yt) {
    __shared__ float T[56 * 57];
    int bd = blockIdx.x;  // b*192+d
    int d = bd % DINC, b = bd / DINC;
    const float* y0 = ys + ((size_t)(b * KDIR + 0) * DINC + d) * LL;
    const float* y1 = ys + ((size_t)(b * KDIR + 1) * DINC + d) * LL;
    const float* y2 = ys + ((size_t)(b * KDIR + 2) * DINC + d) * LL;
    const float* y3 = ys + ((size_t)(b * KDIR + 3) * DINC + d) * LL;
    for (int l = threadIdx.x; l < LL; l += 448)
        T[(l % 56) * 57 + (l / 56)] = y1[l] + y3[LL - 1 - l];
    float sD = dsv[d] + dsv[DINC + d] + dsv[2 * DINC + d] + dsv[3 * DINC + d];
    size_t base = (size_t)bd * LL;
    __syncthreads();
    for (int pos = threadIdx.x; pos < LL; pos += 448) {
        float y = y0[pos] + y2[LL - 1 - pos] + T[(pos / 56) * 57 + (pos % 56)];
        yt[base + pos] = fmaf(xconv[base + pos], sD, y);
    }
}

// ---------- 6. fused out_norm*silu(z) + out_proj + residual ----------
__global__ __launch_bounds__(256) void gemm2_k(const float* __restrict__ yt,
                                               const float* __restrict__ g,
                                               const float* __restrict__ bt,
                                               const float* __restrict__ zs,
                                               const float* __restrict__ opw,
                                               const float* __restrict__ x,
                                               const float* __restrict__ sc1,
                                               float* __restrict__ vl) {
    __shared__ float xT[64 * 193];
    __shared__ float wT[96 * 52];
    __shared__ float mA[64], iA[64];
    int row0 = blockIdx.x * 64;
    int b = row0 / LL, pos0 = row0 % LL;
    for (int f = threadIdx.x; f < 192 * 16; f += 256) {
        int ch = f >> 4, po = (f & 15) * 4;
        float4 v = *(const float4*)&yt[((size_t)b * DINC + ch) * LL + pos0 + po];
        xT[(po + 0) * 193 + ch] = v.x; xT[(po + 1) * 193 + ch] = v.y;
        xT[(po + 2) * 193 + ch] = v.z; xT[(po + 3) * 193 + ch] = v.w;
    }
    __syncthreads();
    if (threadIdx.x < 64) {
        float s = 0.f, q = 0.f;
        const float* xr = &xT[threadIdx.x * 193];
        for (int c = 0; c < 192; ++c) { float v = xr[c]; s += v; q = fmaf(v, v, q); }
        float m = s * (1.f / 192.f);
        mA[threadIdx.x] = m;
        iA[threadIdx.x] = rsqrtf(q * (1.f / 192.f) - m * m + EPSF);
    }
    __syncthreads();
    for (int e = threadIdx.x; e < 64 * 192; e += 256) {
        int row = e / 192, col = e - row * 192;
        float v = xT[row * 193 + col];
        float z = zs[(size_t)row0 * DINC + e];
        xT[row * 193 + col] = ((v - mA[row]) * iA[row] * g[col] + bt[col]) * z;
    }
    int tc = threadIdx.x & 15, tr = threadIdx.x >> 4;
    float acc[4][6] = {};
    for (int kc = 0; kc < 4; ++kc) {
        __syncthreads();
        for (int f = threadIdx.x; f < 96 * 12; f += 256) {
            int r = f / 12, kq = (f % 12) * 4;
            *(float4*)&wT[r * 52 + kq] = *(const float4*)&opw[(size_t)r * DINC + kc * 48 + kq];
        }
        __syncthreads();
        for (int k = 0; k < 48; ++k) {
            float xv[4], wv[6];
#pragma unroll
            for (int i = 0; i < 4; ++i) xv[i] = xT[(4 * tr + i) * 193 + kc * 48 + k];
#pragma unroll
            for (int j = 0; j < 6; ++j) wv[j] = wT[(tc + 16 * j) * 52 + k];
#pragma unroll
            for (int i = 0; i < 4; ++i)
#pragma unroll
                for (int j = 0; j < 6; ++j) acc[i][j] = fmaf(xv[i], wv[j], acc[i][j]);
        }
    }
#pragma unroll
    for (int i = 0; i < 4; ++i) {
        int pos = pos0 + 4 * tr + i;
#pragma unroll
        for (int j = 0; j < 6; ++j) {
            int col = tc + 16 * j;
            float v = fmaf(sc1[col], x[((size_t)b * DIMC + col) * LL + pos], acc[i][j]);
            vl[(size_t)(row0 + 4 * tr + i) * DIMC + col] = v;
        }
    }
}

// ---------- 7. LN2 + conv1x1(96->24) + BN + ReLU ----------
__global__ __launch_bounds__(256) void ln2conv1_k(const float* __restrict__ vl,
                                                  const float* __restrict__ g,
                                                  const float* __restrict__ bt,
                                                  const float* __restrict__ w1,
                                                  const float* __restrict__ g1,
                                                  const float* __restrict__ b1,
                                                  const float* __restrict__ m1,
                                                  const float* __restrict__ v1,
                                                  float* __restrict__ h1) {
    __shared__ float row[4][96];
    int wv = threadIdx.x >> 6, lane = threadIdx.x & 63;
    int pix = blockIdx.x * 4 + wv;
    const float* vr = vl + (size_t)pix * DIMC;
    float a0 = vr[lane];
    float a1 = (lane < 32) ? vr[64 + lane] : 0.f;
    float s = a0 + a1, q = a0 * a0 + a1 * a1;
    for (int o = 32; o; o >>= 1) { s += __shfl_xor(s, o, 64); q += __shfl_xor(q, o, 64); }
    float m = s * (1.f / 96.f);
    float inv = rsqrtf(q * (1.f / 96.f) - m * m + EPSF);
    row[wv][lane] = (a0 - m) * inv * g[lane] + bt[lane];
    if (lane < 32) row[wv][64 + lane] = (a1 - m) * inv * g[64 + lane] + bt[64 + lane];
    __syncthreads();
    if (lane < 24) {
        const float* wr = w1 + lane * 96;
        float acc = 0.f;
#pragma unroll 8
        for (int c = 0; c < 96; ++c) acc = fmaf(row[wv][c], wr[c], acc);
        float bn = (acc - m1[lane]) * rsqrtf(v1[lane] + EPSF) * g1[lane] + b1[lane];
        int b = pix / LL, pos = pix % LL;
        h1[((size_t)b * 24 + lane) * LL + pos] = fmaxf(bn, 0.f);
    }
}

// ---------- 8. conv3x3 (24->24) + BN + ReLU ----------
__global__ __launch_bounds__(256) void conv2_k(const float* __restrict__ h1,
                                               const float* __restrict__ w2,
                                               const float* __restrict__ g2,
                                               const float* __restrict__ b2,
                                               const float* __restrict__ m2,
                                               const float* __restrict__ v2,
                                               float* __restrict__ h2) {
    int i = blockIdx.x * 256 + threadIdx.x;
    int pos = i % LL, mo = (i / LL) % 24, b = i / (LL * 24);
    int hh = pos / WWD, ww = pos % WWD;
    float acc = 0.f;
    for (int c = 0; c < 24; ++c) {
        const float* src = h1 + ((size_t)b * 24 + c) * LL;
        const float* wk = w2 + ((size_t)(mo * 24 + c)) * 9;
#pragma unroll
        for (int ky = 0; ky < 3; ++ky) {
            int y = hh + ky - 1;
            if ((unsigned)y >= HH) continue;
#pragma unroll
            for (int kx = 0; kx < 3; ++kx) {
                int xq = ww + kx - 1;
                if ((unsigned)xq >= WWD) continue;
                acc = fmaf(wk[ky * 3 + kx], src[y * WWD + xq], acc);
            }
        }
    }
    float bn = (acc - m2[mo]) * rsqrtf(v2[mo] + EPSF) * g2[mo] + b2[mo];
    h2[i] = fmaxf(bn, 0.f);
}

// ---------- 9. conv1x1 (24->96) + BN ----------
__global__ __launch_bounds__(256) void conv3_k(const float* __restrict__ h2,
                                               const float* __restrict__ w3,
                                               const float* __restrict__ g3,
                                               const float* __restrict__ b3,
                                               const float* __restrict__ m3,
                                               const float* __restrict__ v3,
                                               float* __restrict__ h3) {
    int i = blockIdx.x * 256 + threadIdx.x;
    int pos = i % LL, c = (i / LL) % DIMC, b = i / (LL * DIMC);
    const float* wr = w3 + c * 24;
    float acc = 0.f;
#pragma unroll
    for (int mo = 0; mo < 24; ++mo)
        acc = fmaf(wr[mo], h2[((size_t)b * 24 + mo) * LL + pos], acc);
    h3[i] = (acc - m3[c]) * rsqrtf(v3[c] + EPSF) * g3[c] + b3[c];
}

// ---------- 10. SE pool ----------
__global__ __launch_bounds__(256) void pool_k(const float* __restrict__ h3,
                                              float* __restrict__ pooled) {
    int bc = blockIdx.x;
    const float* p = h3 + (size_t)bc * LL;
    float s = 0.f;
    for (int i = threadIdx.x; i < LL; i += 256) s += p[i];
    for (int o = 32; o; o >>= 1) s += __shfl_xor(s, o, 64);
    __shared__ float wsum[4];
    if ((threadIdx.x & 63) == 0) wsum[threadIdx.x >> 6] = s;
    __syncthreads();
    if (threadIdx.x == 0) pooled[bc] = (wsum[0] + wsum[1] + wsum[2] + wsum[3]) * (1.f / 3136.f);
}

// ---------- 11. SE MLP ----------
__global__ __launch_bounds__(128) void semlp_k(const float* __restrict__ pooled,
                                               const float* __restrict__ sw1,
                                               const float* __restrict__ sw2,
                                               float* __restrict__ sew) {
    __shared__ float pl[2][96];
    __shared__ float hid[2][24];
    for (int i = threadIdx.x; i < 192; i += 128) pl[i / 96][i % 96] = pooled[i];
    __syncthreads();
    if (threadIdx.x < 48) {
        int b = threadIdx.x / 24, mo = threadIdx.x % 24;
        float acc = 0.f;
        for (int c = 0; c < 96; ++c) acc = fmaf(pl[b][c], sw1[mo * 96 + c], acc);
        hid[b][mo] = fmaxf(acc, 0.f);
    }
    __syncthreads();
    for (int i = threadIdx.x; i < 192; i += 128) {
        int b = i / 96, c = i % 96;
        float acc = 0.f;
        for (int mo = 0; mo < 24; ++mo) acc = fmaf(hid[b][mo], sw2[c * 24 + mo], acc);
        sew[i] = 1.f / (1.f + __expf(-acc));
    }
}

// ---------- 12. final ----------
__global__ __launch_bounds__(256) void final_k(const float* __restrict__ h3,
                                               const float* __restrict__ sew,
                                               const float* __restrict__ vl,
                                               const float* __restrict__ sc2,
                                               float* __restrict__ out) {
    int i = blockIdx.x * 256 + threadIdx.x;
    int pos = i % LL, c = (i / LL) % DIMC, b = i / (LL * DIMC);
    out[i] = fmaf(h3[i], sew[b * DIMC + c],
                  sc2[c] * vl[((size_t)b * LL + pos) * DIMC + c]);
}

extern "C" void kernel_launch(void* const* d_in, const int* in_sizes, int n_in,
                              void* d_out, int out_size, void* d_ws, size_t ws_size,
                              hipStream_t stream) {
    const float* x    = (const float*)d_in[0];
    const float* n1g  = (const float*)d_in[1];
    const float* n1b  = (const float*)d_in[2];
    const float* ipw  = (const float*)d_in[3];
    const float* cw   = (const float*)d_in[4];
    const float* cb   = (const float*)d_in[5];
    const float* xpw  = (const float*)d_in[6];
    const float* dtw  = (const float*)d_in[7];
    const float* dtb  = (const float*)d_in[8];
    const float* alog = (const float*)d_in[9];
    const float* dsv  = (const float*)d_in[10];
    const float* ong  = (const float*)d_in[11];
    const float* onb  = (const float*)d_in[12];
    const float* opw  = (const float*)d_in[13];
    const float* sc1  = (const float*)d_in[14];
    const float* n2g  = (const float*)d_in[15];
    const float* n2b  = (const float*)d_in[16];
    const float* w1   = (const float*)d_in[17];
    const float* g1   = (const float*)d_in[18];
    const float* b1   = (const float*)d_in[19];
    const float* m1   = (const float*)d_in[20];
    const float* v1   = (const float*)d_in[21];
    const float* w2   = (const float*)d_in[22];
    const float* g2   = (const float*)d_in[23];
    const float* b2   = (const float*)d_in[24];
    const float* m2   = (const float*)d_in[25];
    const float* v2   = (const float*)d_in[26];
    const float* w3   = (const float*)d_in[27];
    const float* g3   = (const float*)d_in[28];
    const float* b3   = (const float*)d_in[29];
    const float* m3   = (const float*)d_in[30];
    const float* v3   = (const float*)d_in[31];
    const float* sw1  = (const float*)d_in[32];
    const float* sw2  = (const float*)d_in[33];
    const float* sc2  = (const float*)d_in[34];
    float* ws = (float*)d_ws;
    float* out = (float*)d_out;

    gemm1_k<<<dim3(NPIX / 64, 4), 256, 0, stream>>>(x, n1g, n1b, ipw,
                                                    ws + OFF_XCRAW, ws + OFF_ZS);
    dwconvt_k<<<BB * DINC, 448, 0, stream>>>(ws + OFF_XCRAW, cw, cb,
                                             ws + OFF_XCONV, ws + OFF_XCONVT);
    gemmx_k<<<NPIX / 64, 256, 0, stream>>>(ws + OFF_XCONV, xpw, ws + OFF_DTS, ws + OFF_BC);
    scan_k<<<NCHAIN, NC2 * 16, 0, stream>>>(ws + OFF_DTS, (const float2*)(ws + OFF_BC),
                                            alog, dtw, dtb, ws + OFF_XCONV,
                                            ws + OFF_XCONVT, ws + OFF_YS);
    combine_k<<<BB * DINC, 448, 0, stream>>>(ws + OFF_YS, ws + OFF_XCONV, dsv, ws + OFF_YT);
    gemm2_k<<<NPIX / 64, 256, 0, stream>>>(ws + OFF_YT, ong, onb, ws + OFF_ZS, opw, x, sc1,
                                           ws + OFF_VL);
    ln2conv1_k<<<NPIX / 4, 256, 0, stream>>>(ws + OFF_VL, n2g, n2b, w1, g1, b1, m1, v1,
                                             ws + OFF_H1);
    conv2_k<<<(BB * 24 * LL) / 256, 256, 0, stream>>>(ws + OFF_H1, w2, g2, b2, m2, v2,
                                                      ws + OFF_H2);
    conv3_k<<<(BB * DIMC * LL) / 256, 256, 0, stream>>>(ws + OFF_H2, w3, g3, b3, m3, v3,
                                                        ws + OFF_H3);
    pool_k<<<BB * DIMC, 256, 0, stream>>>(ws + OFF_H3, ws + OFF_POOL);
    semlp_k<<<1, 128, 0, stream>>>(ws + OFF_POOL, sw1, sw2, ws + OFF_SEW);
    final_k<<<(BB * DIMC * LL) / 256, 256, 0, stream>>>(ws + OFF_H3, ws + OFF_SEW, ws + OFF_VL,
                                                        sc2, out);
    (void)in_sizes; (void)n_in; (void)out_size; (void)ws_size;
}

// Round 6
// 305.551 us; speedup vs baseline: 1.8521x; 1.8521x over previous
//
#include <hip/hip_runtime.h>
#include <math.h>

#define DIMC 96
#define DINC 192
#define NSTC 16
#define DTRC 6
#define KDIR 4
#define BB   2
#define HH   56
#define WWD  56
#define LL   3136
#define NPIX (BB*LL)           // 6272
#define EPSF 1e-5f
#define NCH  49                // chunks per chain
#define LC   64                // chunk length
#define NCHAIN (BB*KDIR*DINC)  // 1536
#define NCOLS 152              // 4*38
#define DT   16                // d-chains per scan block
#define NDT  (DINC/DT)         // 12

// ---------- workspace layout (float offsets) ----------
#define OFF_XN     0u          // 602112  sumd during scan; H3 later
#define OFF_XCRAW  602112u     // 1204224 xc pre-conv NCHW; hend during scan; y_t after
#define OFF_ZS     1806336u    // 1204224 silu(z) (B,L,192)
#define OFF_XCONV  3010560u    // 1204224 silu(conv(xc)) NCHW
#define OFF_DTS    4214784u    // 150528  dts (B,K,L,6)
#define OFF_BC     4365312u    // 802816  (B,K,L,16,{B,C})
#define OFF_XCONVT 5168128u    // 1204224 transposed xconv (dead after scan3)
#define OFF_YS     14801920u   // 4816896 ys (B,K,192,L)
#define OFF_HEND   OFF_XCRAW   // 1536*49*16 = 1204224 floats exactly
#define OFF_SUMD   OFF_XN      // 1536*49 = 75264
#define OFF_YT     OFF_XCRAW
#define OFF_VL     OFF_XCONVT              // 602112 (after xconvT dead)
#define OFF_H1     (OFF_XCONVT + 1300000u) // 150528
#define OFF_H2     (OFF_XCONVT + 1500000u) // 150528
#define OFF_H3     OFF_XN
#define OFF_POOL   (OFF_XCONVT + 1700000u)
#define OFF_SEW    (OFF_XCONVT + 1700448u)

__device__ __forceinline__ float siluf(float x) { return x / (1.f + __expf(-x)); }
__device__ __forceinline__ float softplusf(float x) {
    return fmaxf(x, 0.f) + log1pf(__expf(-fabsf(x)));
}

// ---------- 1. fused LN1 + in_proj GEMM. grid (98,4) x 256 ----------
__global__ __launch_bounds__(256) void gemm1_k(const float* __restrict__ x,
                                               const float* __restrict__ g,
                                               const float* __restrict__ bt,
                                               const float* __restrict__ W,
                                               float* __restrict__ xcr,
                                               float* __restrict__ zs) {
    __shared__ float xT[64 * 97];
    __shared__ float wT[96 * 100];
    __shared__ float mA[64], iA[64];
    int row0 = blockIdx.x * 64;
    int b = row0 / LL, pos0 = row0 % LL;
    int c0 = blockIdx.y * 96;
    for (int f = threadIdx.x; f < 96 * 16; f += 256) {
        int ch = f >> 4, po = (f & 15) * 4;
        float4 v = *(const float4*)&x[((size_t)b * DIMC + ch) * LL + pos0 + po];
        xT[(po + 0) * 97 + ch] = v.x; xT[(po + 1) * 97 + ch] = v.y;
        xT[(po + 2) * 97 + ch] = v.z; xT[(po + 3) * 97 + ch] = v.w;
    }
    for (int f = threadIdx.x; f < 96 * 24; f += 256) {
        int r = f / 24, kq = (f % 24) * 4;
        *(float4*)&wT[r * 100 + kq] = *(const float4*)&W[(size_t)(c0 + r) * DIMC + kq];
    }
    __syncthreads();
    if (threadIdx.x < 64) {
        float s = 0.f, q = 0.f;
        const float* xr = &xT[threadIdx.x * 97];
        for (int c = 0; c < 96; ++c) { float v = xr[c]; s += v; q = fmaf(v, v, q); }
        float m = s * (1.f / 96.f);
        mA[threadIdx.x] = m;
        iA[threadIdx.x] = rsqrtf(q * (1.f / 96.f) - m * m + EPSF);
    }
    __syncthreads();
    for (int e = threadIdx.x; e < 64 * 96; e += 256) {
        int row = e / 96, col = e - row * 96;
        float v = xT[row * 97 + col];
        xT[row * 97 + col] = (v - mA[row]) * iA[row] * g[col] + bt[col];
    }
    __syncthreads();
    int tc = threadIdx.x & 15, tr = threadIdx.x >> 4;
    float acc[4][6] = {};
    for (int k = 0; k < 96; ++k) {
        float xv[4], wv[6];
#pragma unroll
        for (int i = 0; i < 4; ++i) xv[i] = xT[(4 * tr + i) * 97 + k];
#pragma unroll
        for (int j = 0; j < 6; ++j) wv[j] = wT[(tc + 16 * j) * 100 + k];
#pragma unroll
        for (int i = 0; i < 4; ++i)
#pragma unroll
            for (int j = 0; j < 6; ++j) acc[i][j] = fmaf(xv[i], wv[j], acc[i][j]);
    }
    int pos = pos0 + 4 * tr;
    if (c0 < DINC) {
#pragma unroll
        for (int j = 0; j < 6; ++j) {
            int col = c0 + tc + 16 * j;
            float4 v = make_float4(acc[0][j], acc[1][j], acc[2][j], acc[3][j]);
            *(float4*)&xcr[((size_t)b * DINC + col) * LL + pos] = v;
        }
    } else {
#pragma unroll
        for (int i = 0; i < 4; ++i)
#pragma unroll
            for (int j = 0; j < 6; ++j) {
                int zc = c0 - DINC + tc + 16 * j;
                zs[(size_t)(row0 + 4 * tr + i) * DINC + zc] = siluf(acc[i][j]);
            }
    }
}

// ---------- 2. depthwise 3x3 conv + silu, emits xconv AND xconvT ----------
__global__ __launch_bounds__(448) void dwconvt_k(const float* __restrict__ xcr,
                                                 const float* __restrict__ cw,
                                                 const float* __restrict__ cb,
                                                 float* __restrict__ xconv,
                                                 float* __restrict__ xconvT) {
    __shared__ float P[56 * 57];
    __shared__ float T[56 * 57];
    int bd = blockIdx.x;
    int d = bd % DINC;
    size_t base = (size_t)bd * LL;
    for (int t = threadIdx.x; t < LL; t += 448)
        P[(t / 56) * 57 + (t % 56)] = xcr[base + t];
    float wk[9];
#pragma unroll
    for (int q = 0; q < 9; ++q) wk[q] = cw[d * 9 + q];
    float bias = cb[d];
    __syncthreads();
    for (int t = threadIdx.x; t < LL; t += 448) {
        int h = t / 56, w = t % 56;
        float acc = bias;
#pragma unroll
        for (int ky = 0; ky < 3; ++ky) {
            int y = h + ky - 1;
            if ((unsigned)y >= 56u) continue;
#pragma unroll
            for (int kx = 0; kx < 3; ++kx) {
                int xq = w + kx - 1;
                if ((unsigned)xq >= 56u) continue;
                acc = fmaf(wk[ky * 3 + kx], P[y * 57 + xq], acc);
            }
        }
        float v = siluf(acc);
        xconv[base + t] = v;
        T[w * 57 + h] = v;
    }
    __syncthreads();
    for (int t = threadIdx.x; t < LL; t += 448)
        xconvT[base + t] = T[(t / 56) * 57 + (t % 56)];
}

// ---------- 3. x_proj LDS-tiled GEMM -> scattered dts/bc. grid 98 x 256 ----------
__global__ __launch_bounds__(256) void gemmx_k(const float* __restrict__ xconv,
                                               const float* __restrict__ xpw,
                                               float* __restrict__ dts,
                                               float* __restrict__ bc) {
    __shared__ float xT[64 * 49];
    __shared__ float wT[NCOLS * 52];
    int row0 = blockIdx.x * 64;
    int b = row0 / LL, pos0 = row0 % LL;
    int tc = threadIdx.x & 15, tr = threadIdx.x >> 4;
    float acc[4][10] = {};
    for (int kc = 0; kc < 4; ++kc) {
        if (kc) __syncthreads();
        for (int f = threadIdx.x; f < 48 * 16; f += 256) {
            int dd = f >> 4, po = (f & 15) * 4;
            float4 v = *(const float4*)&xconv[((size_t)b * DINC + kc * 48 + dd) * LL + pos0 + po];
            xT[(po + 0) * 49 + dd] = v.x; xT[(po + 1) * 49 + dd] = v.y;
            xT[(po + 2) * 49 + dd] = v.z; xT[(po + 3) * 49 + dd] = v.w;
        }
        for (int f = threadIdx.x; f < NCOLS * 12; f += 256) {
            int r = f / 12, kq = (f % 12) * 4;
            *(float4*)&wT[r * 52 + kq] = *(const float4*)&xpw[(size_t)r * DINC + kc * 48 + kq];
        }
        __syncthreads();
        for (int k = 0; k < 48; ++k) {
            float xv[4], wv[10];
#pragma unroll
            for (int i = 0; i < 4; ++i) xv[i] = xT[(4 * tr + i) * 49 + k];
#pragma unroll
            for (int j = 0; j < 10; ++j) {
                int c = tc + 16 * j;
                wv[j] = (c < NCOLS) ? wT[c * 52 + k] : 0.f;
            }
#pragma unroll
            for (int i = 0; i < 4; ++i)
#pragma unroll
                for (int j = 0; j < 10; ++j) acc[i][j] = fmaf(xv[i], wv[j], acc[i][j]);
        }
    }
#pragma unroll
    for (int i = 0; i < 4; ++i) {
        int pos = pos0 + 4 * tr + i;
        int h = pos / 56, w = pos - 56 * h;
        int lt = w * 56 + h;
#pragma unroll
        for (int j = 0; j < 10; ++j) {
            int c = tc + 16 * j;
            if (c >= NCOLS) continue;
            int k = c / 38, idx = c - 38 * k;
            int l = (k == 0) ? pos : (k == 1) ? lt : (k == 2) ? (LL - 1 - pos) : (LL - 1 - lt);
            size_t rb = (size_t)(b * KDIR + k) * LL + l;
            float v = acc[i][j];
            if (idx < DTRC)    dts[rb * DTRC + idx] = v;
            else if (idx < 22) bc[(rb * NSTC + idx - 6) * 2] = v;
            else               bc[(rb * NSTC + idx - 22) * 2 + 1] = v;
        }
    }
}

// ---------- 4a. scan phase 1: LDS-staged, block = (b,k,d-tile,chunk) ----------
// grid: BB*KDIR*NDT*NCH = 4704 blocks x 256
__global__ __launch_bounds__(256) void scan1_k(const float* __restrict__ dts,
                                               const float2* __restrict__ bc2,
                                               const float* __restrict__ alog,
                                               const float* __restrict__ dtw,
                                               const float* __restrict__ dtb,
                                               const float* __restrict__ xconv,
                                               const float* __restrict__ xconvT,
                                               float* __restrict__ hend,
                                               float* __restrict__ sumd) {
    __shared__ float sdt[LC * DTRC];     // 384
    __shared__ float swr[DT * DTRC];     // 96
    __shared__ float sbias[DT];
    __shared__ float sdl[DT * LC];       // 1024
    __shared__ float sdx[DT * LC];       // 1024
    __shared__ float2 sbc[LC * NSTC];    // 1024 float2
    int blk = blockIdx.x;
    int c = blk % NCH;
    int dtile = (blk / NCH) % NDT;
    int bk = blk / (NCH * NDT);
    int k = bk & 3, b = bk >> 2;
    int l0 = c * LC;
    int tid = threadIdx.x;
    const float* dsrc = dts + ((size_t)bk * LL + l0) * DTRC;
    for (int f = tid; f < LC * DTRC; f += 256) sdt[f] = dsrc[f];
    if (tid < DT * DTRC) swr[tid] = dtw[((size_t)k * DINC + dtile * DT) * DTRC + tid];
    if (tid < DT) sbias[tid] = dtb[k * DINC + dtile * DT + tid];
    const float2* bsrc = bc2 + ((size_t)bk * LL + l0) * NSTC;
    for (int f = tid; f < LC * NSTC; f += 256) sbc[f] = bsrc[f];
    bool rev = (k >= 2);
    for (int f = tid; f < DT * LC; f += 256) {
        int d_loc = f >> 6, s = f & 63;
        size_t bd = ((size_t)b * DINC + dtile * DT + d_loc) * LL;
        const float* xs = (k & 1) ? (xconvT + bd) : (xconv + bd);
        sdx[f] = xs[rev ? (LL - 1 - (l0 + s)) : (l0 + s)];
    }
    __syncthreads();
    for (int f = tid; f < DT * LC; f += 256) {
        int d_loc = f >> 6, s = f & 63;
        float acc = sbias[d_loc];
#pragma unroll
        for (int r = 0; r < DTRC; ++r) acc = fmaf(swr[d_loc * DTRC + r], sdt[s * DTRC + r], acc);
        float dv = softplusf(acc);
        sdl[f] = dv;
        sdx[f] = dv * sdx[f];
    }
    __syncthreads();
    int g = tid >> 4, lane = tid & 15;
    int d = dtile * DT + g;
    float An = -__expf(alog[((size_t)(k * DINC + d)) * NSTC + lane]);
    const float* pl = &sdl[g * LC];
    const float* px = &sdx[g * LC];
    float h = 0.f, sd = 0.f;
#pragma unroll 8
    for (int s = 0; s < LC; ++s) {
        float dv = pl[s];
        float2 bcv = sbc[s * NSTC + lane];
        h = fmaf(__expf(dv * An), h, px[s] * bcv.x);
        sd += dv;
    }
    int chain = bk * DINC + d;
    hend[((size_t)chain * NCH + c) * NSTC + lane] = h;
    if (lane == 0) sumd[(size_t)chain * NCH + c] = sd;
}

// ---------- 4b. scan phase 2: sequential combine over chunks (hend -> hpre) ----------
__global__ __launch_bounds__(256) void scan2_k(float* __restrict__ hend,
                                               const float* __restrict__ sumd,
                                               const float* __restrict__ alog) {
    int chain = blockIdx.x * 16 + (threadIdx.x >> 4);
    int lane = threadIdx.x & 15;
    float An = -__expf(alog[(size_t)(chain % (KDIR * DINC)) * NSTC + lane]);
    float* hp = hend + (size_t)chain * NCH * NSTC + lane;
    const float* sp = sumd + (size_t)chain * NCH;
    float h = 0.f;
    for (int c = 0; c < NCH; ++c) {
        float he = hp[(size_t)c * NSTC];
        float sd = sp[c];
        hp[(size_t)c * NSTC] = h;
        h = fmaf(__expf(An * sd), h, he);
    }
}

// ---------- 4c. scan phase 3: LDS-staged re-scan, emit y ----------
__global__ __launch_bounds__(256) void scan3_k(const float* __restrict__ dts,
                                               const float2* __restrict__ bc2,
                                               const float* __restrict__ alog,
                                               const float* __restrict__ dtw,
                                               const float* __restrict__ dtb,
                                               const float* __restrict__ xconv,
                                               const float* __restrict__ xconvT,
                                               const float* __restrict__ hpre,
                                               float* __restrict__ ys) {
    __shared__ float sdt[LC * DTRC];
    __shared__ float swr[DT * DTRC];
    __shared__ float sbias[DT];
    __shared__ float sdl[DT * LC];
    __shared__ float sdx[DT * LC];
    __shared__ float sy[DT * LC];
    __shared__ float2 sbc[LC * NSTC];
    int blk = blockIdx.x;
    int c = blk % NCH;
    int dtile = (blk / NCH) % NDT;
    int bk = blk / (NCH * NDT);
    int k = bk & 3, b = bk >> 2;
    int l0 = c * LC;
    int tid = threadIdx.x;
    const float* dsrc = dts + ((size_t)bk * LL + l0) * DTRC;
    for (int f = tid; f < LC * DTRC; f += 256) sdt[f] = dsrc[f];
    if (tid < DT * DTRC) swr[tid] = dtw[((size_t)k * DINC + dtile * DT) * DTRC + tid];
    if (tid < DT) sbias[tid] = dtb[k * DINC + dtile * DT + tid];
    const float2* bsrc = bc2 + ((size_t)bk * LL + l0) * NSTC;
    for (int f = tid; f < LC * NSTC; f += 256) sbc[f] = bsrc[f];
    bool rev = (k >= 2);
    for (int f = tid; f < DT * LC; f += 256) {
        int d_loc = f >> 6, s = f & 63;
        size_t bd = ((size_t)b * DINC + dtile * DT + d_loc) * LL;
        const float* xs = (k & 1) ? (xconvT + bd) : (xconv + bd);
        sdx[f] = xs[rev ? (LL - 1 - (l0 + s)) : (l0 + s)];
    }
    __syncthreads();
    for (int f = tid; f < DT * LC; f += 256) {
        int d_loc = f >> 6, s = f & 63;
        float acc = sbias[d_loc];
#pragma unroll
        for (int r = 0; r < DTRC; ++r) acc = fmaf(swr[d_loc * DTRC + r], sdt[s * DTRC + r], acc);
        float dv = softplusf(acc);
        sdl[f] = dv;
        sdx[f] = dv * sdx[f];
    }
    __syncthreads();
    int g = tid >> 4, lane = tid & 15;
    int d = dtile * DT + g;
    float An = -__expf(alog[((size_t)(k * DINC + d)) * NSTC + lane]);
    int chain = bk * DINC + d;
    const float* pl = &sdl[g * LC];
    const float* px = &sdx[g * LC];
    float h = hpre[((size_t)chain * NCH + c) * NSTC + lane];
#pragma unroll 4
    for (int s = 0; s < LC; ++s) {
        float2 bcv = sbc[s * NSTC + lane];
        h = fmaf(__expf(pl[s] * An), h, px[s] * bcv.x);
        float p = h * bcv.y;
        p += __shfl_xor(p, 1, 16);
        p += __shfl_xor(p, 2, 16);
        p += __shfl_xor(p, 4, 16);
        p += __shfl_xor(p, 8, 16);
        if (lane == 0) sy[g * LC + s] = p;
    }
    __syncthreads();
    float* yo = ys + ((size_t)bk * DINC + dtile * DT) * LL + l0;
    {
        int d_loc = tid >> 4, s4 = tid & 15;  // 256 threads = 16x16 float4
        *(float4*)&yo[(size_t)d_loc * LL + s4 * 4] = *(const float4*)&sy[d_loc * LC + s4 * 4];
    }
}

// ---------- 5. combine 4 directions (+ D*x) with in-LDS transpose ----------
__global__ __launch_bounds__(448) void combine_k(const float* __restrict__ ys,
                                                 const float* __restrict__ xconv,
                                                 const float* __restrict__ dsv,
                                                 float* __restrict__ yt) {
    __shared__ float T[56 * 57];
    int bd = blockIdx.x;
    int d = bd % DINC, b = bd / DINC;
    const float* y0 = ys + ((size_t)(b * KDIR + 0) * DINC + d) * LL;
    const float* y1 = ys + ((size_t)(b * KDIR + 1) * DINC + d) * LL;
    const float* y2 = ys + ((size_t)(b * KDIR + 2) * DINC + d) * LL;
    const float* y3 = ys + ((size_t)(b * KDIR + 3) * DINC + d) * LL;
    for (int l = threadIdx.x; l < LL; l += 448)
        T[(l % 56) * 57 + (l / 56)] = y1[l] + y3[LL - 1 - l];
    float sD = dsv[d] + dsv[DINC + d] + dsv[2 * DINC + d] + dsv[3 * DINC + d];
    size_t base = (size_t)bd * LL;
    __syncthreads();
    for (int pos = threadIdx.x; pos < LL; pos += 448) {
        float y = y0[pos] + y2[LL - 1 - pos] + T[(pos / 56) * 57 + (pos % 56)];
        yt[base + pos] = fmaf(xconv[base + pos], sD, y);
    }
}

// ---------- 6. fused out_norm*silu(z) + out_proj + residual ----------
__global__ __launch_bounds__(256) void gemm2_k(const float* __restrict__ yt,
                                               const float* __restrict__ g,
                                               const float* __restrict__ bt,
                                               const float* __restrict__ zs,
                                               const float* __restrict__ opw,
                                               const float* __restrict__ x,
                                               const float* __restrict__ sc1,
                                               float* __restrict__ vl) {
    __shared__ float xT[64 * 193];
    __shared__ float wT[96 * 52];
    __shared__ float mA[64], iA[64];
    int row0 = blockIdx.x * 64;
    int b = row0 / LL, pos0 = row0 % LL;
    for (int f = threadIdx.x; f < 192 * 16; f += 256) {
        int ch = f >> 4, po = (f & 15) * 4;
        float4 v = *(const float4*)&yt[((size_t)b * DINC + ch) * LL + pos0 + po];
        xT[(po + 0) * 193 + ch] = v.x; xT[(po + 1) * 193 + ch] = v.y;
        xT[(po + 2) * 193 + ch] = v.z; xT[(po + 3) * 193 + ch] = v.w;
    }
    __syncthreads();
    if (threadIdx.x < 64) {
        float s = 0.f, q = 0.f;
        const float* xr = &xT[threadIdx.x * 193];
        for (int c = 0; c < 192; ++c) { float v = xr[c]; s += v; q = fmaf(v, v, q); }
        float m = s * (1.f / 192.f);
        mA[threadIdx.x] = m;
        iA[threadIdx.x] = rsqrtf(q * (1.f / 192.f) - m * m + EPSF);
    }
    __syncthreads();
    for (int e = threadIdx.x; e < 64 * 192; e += 256) {
        int row = e / 192, col = e - row * 192;
        float v = xT[row * 193 + col];
        float z = zs[(size_t)row0 * DINC + e];
        xT[row * 193 + col] = ((v - mA[row]) * iA[row] * g[col] + bt[col]) * z;
    }
    int tc = threadIdx.x & 15, tr = threadIdx.x >> 4;
    float acc[4][6] = {};
    for (int kc = 0; kc < 4; ++kc) {
        __syncthreads();
        for (int f = threadIdx.x; f < 96 * 12; f += 256) {
            int r = f / 12, kq = (f % 12) * 4;
            *(float4*)&wT[r * 52 + kq] = *(const float4*)&opw[(size_t)r * DINC + kc * 48 + kq];
        }
        __syncthreads();
        for (int k = 0; k < 48; ++k) {
            float xv[4], wv[6];
#pragma unroll
            for (int i = 0; i < 4; ++i) xv[i] = xT[(4 * tr + i) * 193 + kc * 48 + k];
#pragma unroll
            for (int j = 0; j < 6; ++j) wv[j] = wT[(tc + 16 * j) * 52 + k];
#pragma unroll
            for (int i = 0; i < 4; ++i)
#pragma unroll
                for (int j = 0; j < 6; ++j) acc[i][j] = fmaf(xv[i], wv[j], acc[i][j]);
        }
    }
#pragma unroll
    for (int i = 0; i < 4; ++i) {
        int pos = pos0 + 4 * tr + i;
#pragma unroll
        for (int j = 0; j < 6; ++j) {
            int col = tc + 16 * j;
            float v = fmaf(sc1[col], x[((size_t)b * DIMC + col) * LL + pos], acc[i][j]);
            vl[(size_t)(row0 + 4 * tr + i) * DIMC + col] = v;
        }
    }
}

// ---------- 7. LN2 + conv1x1(96->24) + BN + ReLU ----------
__global__ __launch_bounds__(256) void ln2conv1_k(const float* __restrict__ vl,
                                                  const float* __restrict__ g,
                                                  const float* __restrict__ bt,
                                                  const float* __restrict__ w1,
                                                  const float* __restrict__ g1,
                                                  const float* __restrict__ b1,
                                                  const float* __restrict__ m1,
                                                  const float* __restrict__ v1,
                                                  float* __restrict__ h1) {
    __shared__ float row[4][96];
    int wv = threadIdx.x >> 6, lane = threadIdx.x & 63;
    int pix = blockIdx.x * 4 + wv;
    const float* vr = vl + (size_t)pix * DIMC;
    float a0 = vr[lane];
    float a1 = (lane < 32) ? vr[64 + lane] : 0.f;
    float s = a0 + a1, q = a0 * a0 + a1 * a1;
    for (int o = 32; o; o >>= 1) { s += __shfl_xor(s, o, 64); q += __shfl_xor(q, o, 64); }
    float m = s * (1.f / 96.f);
    float inv = rsqrtf(q * (1.f / 96.f) - m * m + EPSF);
    row[wv][lane] = (a0 - m) * inv * g[lane] + bt[lane];
    if (lane < 32) row[wv][64 + lane] = (a1 - m) * inv * g[64 + lane] + bt[64 + lane];
    __syncthreads();
    if (lane < 24) {
        const float* wr = w1 + lane * 96;
        float acc = 0.f;
#pragma unroll 8
        for (int c = 0; c < 96; ++c) acc = fmaf(row[wv][c], wr[c], acc);
        float bn = (acc - m1[lane]) * rsqrtf(v1[lane] + EPSF) * g1[lane] + b1[lane];
        int b = pix / LL, pos = pix % LL;
        h1[((size_t)b * 24 + lane) * LL + pos] = fmaxf(bn, 0.f);
    }
}

// ---------- 8. conv3x3 (24->24) + BN + ReLU ----------
__global__ __launch_bounds__(256) void conv2_k(const float* __restrict__ h1,
                                               const float* __restrict__ w2,
                                               const float* __restrict__ g2,
                                               const float* __restrict__ b2,
                                               const float* __restrict__ m2,
                                               const float* __restrict__ v2,
                                               float* __restrict__ h2) {
    int i = blockIdx.x * 256 + threadIdx.x;
    int pos = i % LL, mo = (i / LL) % 24, b = i / (LL * 24);
    int hh = pos / WWD, ww = pos % WWD;
    float acc = 0.f;
    for (int c = 0; c < 24; ++c) {
        const float* src = h1 + ((size_t)b * 24 + c) * LL;
        const float* wk = w2 + ((size_t)(mo * 24 + c)) * 9;
#pragma unroll
        for (int ky = 0; ky < 3; ++ky) {
            int y = hh + ky - 1;
            if ((unsigned)y >= HH) continue;
#pragma unroll
            for (int kx = 0; kx < 3; ++kx) {
                int xq = ww + kx - 1;
                if ((unsigned)xq >= WWD) continue;
                acc = fmaf(wk[ky * 3 + kx], src[y * WWD + xq], acc);
            }
        }
    }
    float bn = (acc - m2[mo]) * rsqrtf(v2[mo] + EPSF) * g2[mo] + b2[mo];
    h2[i] = fmaxf(bn, 0.f);
}

// ---------- 9. conv1x1 (24->96) + BN ----------
__global__ __launch_bounds__(256) void conv3_k(const float* __restrict__ h2,
                                               const float* __restrict__ w3,
                                               const float* __restrict__ g3,
                                               const float* __restrict__ b3,
                                               const float* __restrict__ m3,
                                               const float* __restrict__ v3,
                                               float* __restrict__ h3) {
    int i = blockIdx.x * 256 + threadIdx.x;
    int pos = i % LL, c = (i / LL) % DIMC, b = i / (LL * DIMC);
    const float* wr = w3 + c * 24;
    float acc = 0.f;
#pragma unroll
    for (int mo = 0; mo < 24; ++mo)
        acc = fmaf(wr[mo], h2[((size_t)b * 24 + mo) * LL + pos], acc);
    h3[i] = (acc - m3[c]) * rsqrtf(v3[c] + EPSF) * g3[c] + b3[c];
}

// ---------- 10. SE pool ----------
__global__ __launch_bounds__(256) void pool_k(const float* __restrict__ h3,
                                              float* __restrict__ pooled) {
    int bc = blockIdx.x;
    const float* p = h3 + (size_t)bc * LL;
    float s = 0.f;
    for (int i = threadIdx.x; i < LL; i += 256) s += p[i];
    for (int o = 32; o; o >>= 1) s += __shfl_xor(s, o, 64);
    __shared__ float wsum[4];
    if ((threadIdx.x & 63) == 0) wsum[threadIdx.x >> 6] = s;
    __syncthreads();
    if (threadIdx.x == 0) pooled[bc] = (wsum[0] + wsum[1] + wsum[2] + wsum[3]) * (1.f / 3136.f);
}

// ---------- 11. SE MLP ----------
__global__ __launch_bounds__(128) void semlp_k(const float* __restrict__ pooled,
                                               const float* __restrict__ sw1,
                                               const float* __restrict__ sw2,
                                               float* __restrict__ sew) {
    __shared__ float pl[2][96];
    __shared__ float hid[2][24];
    for (int i = threadIdx.x; i < 192; i += 128) pl[i / 96][i % 96] = pooled[i];
    __syncthreads();
    if (threadIdx.x < 48) {
        int b = threadIdx.x / 24, mo = threadIdx.x % 24;
        float acc = 0.f;
        for (int c = 0; c < 96; ++c) acc = fmaf(pl[b][c], sw1[mo * 96 + c], acc);
        hid[b][mo] = fmaxf(acc, 0.f);
    }
    __syncthreads();
    for (int i = threadIdx.x; i < 192; i += 128) {
        int b = i / 96, c = i % 96;
        float acc = 0.f;
        for (int mo = 0; mo < 24; ++mo) acc = fmaf(hid[b][mo], sw2[c * 24 + mo], acc);
        sew[i] = 1.f / (1.f + __expf(-acc));
    }
}

// ---------- 12. final ----------
__global__ __launch_bounds__(256) void final_k(const float* __restrict__ h3,
                                               const float* __restrict__ sew,
                                               const float* __restrict__ vl,
                                               const float* __restrict__ sc2,
                                               float* __restrict__ out) {
    int i = blockIdx.x * 256 + threadIdx.x;
    int pos = i % LL, c = (i / LL) % DIMC, b = i / (LL * DIMC);
    out[i] = fmaf(h3[i], sew[b * DIMC + c],
                  sc2[c] * vl[((size_t)b * LL + pos) * DIMC + c]);
}

extern "C" void kernel_launch(void* const* d_in, const int* in_sizes, int n_in,
                              void* d_out, int out_size, void* d_ws, size_t ws_size,
                              hipStream_t stream) {
    const float* x    = (const float*)d_in[0];
    const float* n1g  = (const float*)d_in[1];
    const float* n1b  = (const float*)d_in[2];
    const float* ipw  = (const float*)d_in[3];
    const float* cw   = (const float*)d_in[4];
    const float* cb   = (const float*)d_in[5];
    const float* xpw  = (const float*)d_in[6];
    const float* dtw  = (const float*)d_in[7];
    const float* dtb  = (const float*)d_in[8];
    const float* alog = (const float*)d_in[9];
    const float* dsv  = (const float*)d_in[10];
    const float* ong  = (const float*)d_in[11];
    const float* onb  = (const float*)d_in[12];
    const float* opw  = (const float*)d_in[13];
    const float* sc1  = (const float*)d_in[14];
    const float* n2g  = (const float*)d_in[15];
    const float* n2b  = (const float*)d_in[16];
    const float* w1   = (const float*)d_in[17];
    const float* g1   = (const float*)d_in[18];
    const float* b1   = (const float*)d_in[19];
    const float* m1   = (const float*)d_in[20];
    const float* v1   = (const float*)d_in[21];
    const float* w2   = (const float*)d_in[22];
    const float* g2   = (const float*)d_in[23];
    const float* b2   = (const float*)d_in[24];
    const float* m2   = (const float*)d_in[25];
    const float* v2   = (const float*)d_in[26];
    const float* w3   = (const float*)d_in[27];
    const float* g3   = (const float*)d_in[28];
    const float* b3   = (const float*)d_in[29];
    const float* m3   = (const float*)d_in[30];
    const float* v3   = (const float*)d_in[31];
    const float* sw1  = (const float*)d_in[32];
    const float* sw2  = (const float*)d_in[33];
    const float* sc2  = (const float*)d_in[34];
    float* ws = (float*)d_ws;
    float* out = (float*)d_out;

    gemm1_k<<<dim3(NPIX / 64, 4), 256, 0, stream>>>(x, n1g, n1b, ipw,
                                                    ws + OFF_XCRAW, ws + OFF_ZS);
    dwconvt_k<<<BB * DINC, 448, 0, stream>>>(ws + OFF_XCRAW, cw, cb,
                                             ws + OFF_XCONV, ws + OFF_XCONVT);
    gemmx_k<<<NPIX / 64, 256, 0, stream>>>(ws + OFF_XCONV, xpw, ws + OFF_DTS, ws + OFF_BC);

    scan1_k<<<BB * KDIR * NDT * NCH, 256, 0, stream>>>(
        ws + OFF_DTS, (const float2*)(ws + OFF_BC), alog, dtw, dtb,
        ws + OFF_XCONV, ws + OFF_XCONVT, ws + OFF_HEND, ws + OFF_SUMD);
    scan2_k<<<NCHAIN / 16, 256, 0, stream>>>(ws + OFF_HEND, ws + OFF_SUMD, alog);
    scan3_k<<<BB * KDIR * NDT * NCH, 256, 0, stream>>>(
        ws + OFF_DTS, (const float2*)(ws + OFF_BC), alog, dtw, dtb,
        ws + OFF_XCONV, ws + OFF_XCONVT, ws + OFF_HEND, ws + OFF_YS);

    combine_k<<<BB * DINC, 448, 0, stream>>>(ws + OFF_YS, ws + OFF_XCONV, dsv, ws + OFF_YT);
    gemm2_k<<<NPIX / 64, 256, 0, stream>>>(ws + OFF_YT, ong, onb, ws + OFF_ZS, opw, x, sc1,
                                           ws + OFF_VL);
    ln2conv1_k<<<NPIX / 4, 256, 0, stream>>>(ws + OFF_VL, n2g, n2b, w1, g1, b1, m1, v1,
                                             ws + OFF_H1);
    conv2_k<<<(BB * 24 * LL) / 256, 256, 0, stream>>>(ws + OFF_H1, w2, g2, b2, m2, v2,
                                                      ws + OFF_H2);
    conv3_k<<<(BB * DIMC * LL) / 256, 256, 0, stream>>>(ws + OFF_H2, w3, g3, b3, m3, v3,
                                                        ws + OFF_H3);
    pool_k<<<BB * DIMC, 256, 0, stream>>>(ws + OFF_H3, ws + OFF_POOL);
    semlp_k<<<1, 128, 0, stream>>>(ws + OFF_POOL, sw1, sw2, ws + OFF_SEW);
    final_k<<<(BB * DIMC * LL) / 256, 256, 0, stream>>>(ws + OFF_H3, ws + OFF_SEW, ws + OFF_VL,
                                                        sc2, out);
    (void)in_sizes; (void)n_in; (void)out_size; (void)ws_size;
}

// Round 7
// 289.204 us; speedup vs baseline: 1.9568x; 1.0565x over previous
//
#include <hip/hip_runtime.h>
#include <math.h>

#define DIMC 96
#define DINC 192
#define NSTC 16
#define DTRC 6
#define KDIR 4
#define BB   2
#define HH   56
#define WWD  56
#define LL   3136
#define NPIX (BB*LL)           // 6272
#define EPSF 1e-5f
#define NCH  49                // chunks per chain
#define LC   64                // chunk length
#define LCP  65                // padded stride (kills cross-group bank conflicts)
#define NCHAIN (BB*KDIR*DINC)  // 1536
#define NCOLS 152              // 4*38
#define DT   16                // d-chains per scan block
#define NDT  (DINC/DT)         // 12

// ---------- workspace layout (float offsets) ----------
#define OFF_XN     0u          // 602112  sumd during scan; H3 later
#define OFF_XCRAW  602112u     // 1204224 xc pre-conv NCHW; hend during scan; y_t after
#define OFF_ZS     1806336u    // 1204224 silu(z) (B,L,192)
#define OFF_XCONV  3010560u    // 1204224 silu(conv(xc)) NCHW
#define OFF_DTS    4214784u    // 150528  dts (B,K,L,6)
#define OFF_BC     4365312u    // 802816  (B,K,L,16,{B,C})
#define OFF_XCONVT 5168128u    // 1204224 transposed xconv (dead after scan3)
#define OFF_YS     14801920u   // 4816896 ys (B,K,192,L)
#define OFF_HEND   OFF_XCRAW   // 1536*49*16 = 1204224 floats exactly
#define OFF_SUMD   OFF_XN      // 1536*49 = 75264
#define OFF_YT     OFF_XCRAW
#define OFF_VL     OFF_XCONVT              // 602112 (after xconvT dead)
#define OFF_H1     (OFF_XCONVT + 1300000u) // 150528
#define OFF_H2     (OFF_XCONVT + 1500000u) // 150528
#define OFF_H3     OFF_XN
#define OFF_POOL   (OFF_XCONVT + 1700000u)
#define OFF_SEW    (OFF_XCONVT + 1700448u)

__device__ __forceinline__ float siluf(float x) { return x / (1.f + __expf(-x)); }
__device__ __forceinline__ float softplusf(float x) {
    // fast: max(x,0) + log(1+exp(-|x|)); accuracy ~1e-6 rel, fine vs 2e-2 threshold
    return fmaxf(x, 0.f) + __logf(1.f + __expf(-fabsf(x)));
}

// ---------- 1. fused LN1 + in_proj GEMM. grid (98,4) x 256 ----------
__global__ __launch_bounds__(256) void gemm1_k(const float* __restrict__ x,
                                               const float* __restrict__ g,
                                               const float* __restrict__ bt,
                                               const float* __restrict__ W,
                                               float* __restrict__ xcr,
                                               float* __restrict__ zs) {
    __shared__ float xT[64 * 97];
    __shared__ float wT[96 * 100];
    __shared__ float mA[64], iA[64];
    int row0 = blockIdx.x * 64;
    int b = row0 / LL, pos0 = row0 % LL;
    int c0 = blockIdx.y * 96;
    for (int f = threadIdx.x; f < 96 * 16; f += 256) {
        int ch = f >> 4, po = (f & 15) * 4;
        float4 v = *(const float4*)&x[((size_t)b * DIMC + ch) * LL + pos0 + po];
        xT[(po + 0) * 97 + ch] = v.x; xT[(po + 1) * 97 + ch] = v.y;
        xT[(po + 2) * 97 + ch] = v.z; xT[(po + 3) * 97 + ch] = v.w;
    }
    for (int f = threadIdx.x; f < 96 * 24; f += 256) {
        int r = f / 24, kq = (f % 24) * 4;
        *(float4*)&wT[r * 100 + kq] = *(const float4*)&W[(size_t)(c0 + r) * DIMC + kq];
    }
    __syncthreads();
    if (threadIdx.x < 64) {
        float s = 0.f, q = 0.f;
        const float* xr = &xT[threadIdx.x * 97];
        for (int c = 0; c < 96; ++c) { float v = xr[c]; s += v; q = fmaf(v, v, q); }
        float m = s * (1.f / 96.f);
        mA[threadIdx.x] = m;
        iA[threadIdx.x] = rsqrtf(q * (1.f / 96.f) - m * m + EPSF);
    }
    __syncthreads();
    for (int e = threadIdx.x; e < 64 * 96; e += 256) {
        int row = e / 96, col = e - row * 96;
        float v = xT[row * 97 + col];
        xT[row * 97 + col] = (v - mA[row]) * iA[row] * g[col] + bt[col];
    }
    __syncthreads();
    int tc = threadIdx.x & 15, tr = threadIdx.x >> 4;
    float acc[4][6] = {};
    for (int k = 0; k < 96; ++k) {
        float xv[4], wv[6];
#pragma unroll
        for (int i = 0; i < 4; ++i) xv[i] = xT[(4 * tr + i) * 97 + k];
#pragma unroll
        for (int j = 0; j < 6; ++j) wv[j] = wT[(tc + 16 * j) * 100 + k];
#pragma unroll
        for (int i = 0; i < 4; ++i)
#pragma unroll
            for (int j = 0; j < 6; ++j) acc[i][j] = fmaf(xv[i], wv[j], acc[i][j]);
    }
    int pos = pos0 + 4 * tr;
    if (c0 < DINC) {
#pragma unroll
        for (int j = 0; j < 6; ++j) {
            int col = c0 + tc + 16 * j;
            float4 v = make_float4(acc[0][j], acc[1][j], acc[2][j], acc[3][j]);
            *(float4*)&xcr[((size_t)b * DINC + col) * LL + pos] = v;
        }
    } else {
#pragma unroll
        for (int i = 0; i < 4; ++i)
#pragma unroll
            for (int j = 0; j < 6; ++j) {
                int zc = c0 - DINC + tc + 16 * j;
                zs[(size_t)(row0 + 4 * tr + i) * DINC + zc] = siluf(acc[i][j]);
            }
    }
}

// ---------- 2. depthwise 3x3 conv + silu, emits xconv AND xconvT ----------
__global__ __launch_bounds__(448) void dwconvt_k(const float* __restrict__ xcr,
                                                 const float* __restrict__ cw,
                                                 const float* __restrict__ cb,
                                                 float* __restrict__ xconv,
                                                 float* __restrict__ xconvT) {
    __shared__ float P[56 * 57];
    __shared__ float T[56 * 57];
    int bd = blockIdx.x;
    int d = bd % DINC;
    size_t base = (size_t)bd * LL;
    for (int t = threadIdx.x; t < LL; t += 448)
        P[(t / 56) * 57 + (t % 56)] = xcr[base + t];
    float wk[9];
#pragma unroll
    for (int q = 0; q < 9; ++q) wk[q] = cw[d * 9 + q];
    float bias = cb[d];
    __syncthreads();
    for (int t = threadIdx.x; t < LL; t += 448) {
        int h = t / 56, w = t % 56;
        float acc = bias;
#pragma unroll
        for (int ky = 0; ky < 3; ++ky) {
            int y = h + ky - 1;
            if ((unsigned)y >= 56u) continue;
#pragma unroll
            for (int kx = 0; kx < 3; ++kx) {
                int xq = w + kx - 1;
                if ((unsigned)xq >= 56u) continue;
                acc = fmaf(wk[ky * 3 + kx], P[y * 57 + xq], acc);
            }
        }
        float v = siluf(acc);
        xconv[base + t] = v;
        T[w * 57 + h] = v;
    }
    __syncthreads();
    for (int t = threadIdx.x; t < LL; t += 448)
        xconvT[base + t] = T[(t / 56) * 57 + (t % 56)];
}

// ---------- 3. x_proj LDS-tiled GEMM -> scattered dts/bc. grid 98 x 256 ----------
__global__ __launch_bounds__(256) void gemmx_k(const float* __restrict__ xconv,
                                               const float* __restrict__ xpw,
                                               float* __restrict__ dts,
                                               float* __restrict__ bc) {
    __shared__ float xT[64 * 49];
    __shared__ float wT[NCOLS * 52];
    int row0 = blockIdx.x * 64;
    int b = row0 / LL, pos0 = row0 % LL;
    int tc = threadIdx.x & 15, tr = threadIdx.x >> 4;
    float acc[4][10] = {};
    for (int kc = 0; kc < 4; ++kc) {
        if (kc) __syncthreads();
        for (int f = threadIdx.x; f < 48 * 16; f += 256) {
            int dd = f >> 4, po = (f & 15) * 4;
            float4 v = *(const float4*)&xconv[((size_t)b * DINC + kc * 48 + dd) * LL + pos0 + po];
            xT[(po + 0) * 49 + dd] = v.x; xT[(po + 1) * 49 + dd] = v.y;
            xT[(po + 2) * 49 + dd] = v.z; xT[(po + 3) * 49 + dd] = v.w;
        }
        for (int f = threadIdx.x; f < NCOLS * 12; f += 256) {
            int r = f / 12, kq = (f % 12) * 4;
            *(float4*)&wT[r * 52 + kq] = *(const float4*)&xpw[(size_t)r * DINC + kc * 48 + kq];
        }
        __syncthreads();
        for (int k = 0; k < 48; ++k) {
            float xv[4], wv[10];
#pragma unroll
            for (int i = 0; i < 4; ++i) xv[i] = xT[(4 * tr + i) * 49 + k];
#pragma unroll
            for (int j = 0; j < 10; ++j) {
                int c = tc + 16 * j;
                wv[j] = (c < NCOLS) ? wT[c * 52 + k] : 0.f;
            }
#pragma unroll
            for (int i = 0; i < 4; ++i)
#pragma unroll
                for (int j = 0; j < 10; ++j) acc[i][j] = fmaf(xv[i], wv[j], acc[i][j]);
        }
    }
#pragma unroll
    for (int i = 0; i < 4; ++i) {
        int pos = pos0 + 4 * tr + i;
        int h = pos / 56, w = pos - 56 * h;
        int lt = w * 56 + h;
#pragma unroll
        for (int j = 0; j < 10; ++j) {
            int c = tc + 16 * j;
            if (c >= NCOLS) continue;
            int k = c / 38, idx = c - 38 * k;
            int l = (k == 0) ? pos : (k == 1) ? lt : (k == 2) ? (LL - 1 - pos) : (LL - 1 - lt);
            size_t rb = (size_t)(b * KDIR + k) * LL + l;
            float v = acc[i][j];
            if (idx < DTRC)    dts[rb * DTRC + idx] = v;
            else if (idx < 22) bc[(rb * NSTC + idx - 6) * 2] = v;
            else               bc[(rb * NSTC + idx - 22) * 2 + 1] = v;
        }
    }
}

// ---------- 4a. scan phase 1: LDS-staged, block = (b,k,d-tile,chunk) ----------
__global__ __launch_bounds__(256) void scan1_k(const float* __restrict__ dts,
                                               const float2* __restrict__ bc2,
                                               const float* __restrict__ alog,
                                               const float* __restrict__ dtw,
                                               const float* __restrict__ dtb,
                                               const float* __restrict__ xconv,
                                               const float* __restrict__ xconvT,
                                               float* __restrict__ hend,
                                               float* __restrict__ sumd) {
    __shared__ float sdt[LC * DTRC];
    __shared__ float swr[DT * DTRC];
    __shared__ float sbias[DT];
    __shared__ float sdl[DT * LCP];      // padded: bank = (g+s)%32, conflict-free
    __shared__ float sdx[DT * LCP];
    __shared__ float2 sbc[LC * NSTC];
    int blk = blockIdx.x;
    int c = blk % NCH;
    int dtile = (blk / NCH) % NDT;
    int bk = blk / (NCH * NDT);
    int k = bk & 3, b = bk >> 2;
    int l0 = c * LC;
    int tid = threadIdx.x;
    const float* dsrc = dts + ((size_t)bk * LL + l0) * DTRC;
    for (int f = tid; f < LC * DTRC; f += 256) sdt[f] = dsrc[f];
    if (tid < DT * DTRC) swr[tid] = dtw[((size_t)k * DINC + dtile * DT) * DTRC + tid];
    if (tid < DT) sbias[tid] = dtb[k * DINC + dtile * DT + tid];
    const float2* bsrc = bc2 + ((size_t)bk * LL + l0) * NSTC;
    for (int f = tid; f < LC * NSTC; f += 256) sbc[f] = bsrc[f];
    bool rev = (k >= 2);
    for (int f = tid; f < DT * LC; f += 256) {
        int d_loc = f >> 6, s = f & 63;
        size_t bd = ((size_t)b * DINC + dtile * DT + d_loc) * LL;
        const float* xs = (k & 1) ? (xconvT + bd) : (xconv + bd);
        sdx[d_loc * LCP + s] = xs[rev ? (LL - 1 - (l0 + s)) : (l0 + s)];
    }
    __syncthreads();
    for (int f = tid; f < DT * LC; f += 256) {
        int d_loc = f >> 6, s = f & 63;
        float acc = sbias[d_loc];
#pragma unroll
        for (int r = 0; r < DTRC; ++r) acc = fmaf(swr[d_loc * DTRC + r], sdt[s * DTRC + r], acc);
        float dv = softplusf(acc);
        sdl[d_loc * LCP + s] = dv;
        sdx[d_loc * LCP + s] *= dv;
    }
    __syncthreads();
    int g = tid >> 4, lane = tid & 15;
    int d = dtile * DT + g;
    float An = -__expf(alog[((size_t)(k * DINC + d)) * NSTC + lane]);
    const float* pl = &sdl[g * LCP];
    const float* px = &sdx[g * LCP];
    float h = 0.f, sd = 0.f;
#pragma unroll 8
    for (int s = 0; s < LC; ++s) {
        float dv = pl[s];
        float2 bcv = sbc[s * NSTC + lane];
        h = fmaf(__expf(dv * An), h, px[s] * bcv.x);
        sd += dv;
    }
    int chain = bk * DINC + d;
    hend[((size_t)chain * NCH + c) * NSTC + lane] = h;
    if (lane == 0) sumd[(size_t)chain * NCH + c] = sd;
}

// ---------- 4b. scan phase 2: sequential combine over chunks (hend -> hpre) ----------
__global__ __launch_bounds__(256) void scan2_k(float* __restrict__ hend,
                                               const float* __restrict__ sumd,
                                               const float* __restrict__ alog) {
    int chain = blockIdx.x * 16 + (threadIdx.x >> 4);
    int lane = threadIdx.x & 15;
    float An = -__expf(alog[(size_t)(chain % (KDIR * DINC)) * NSTC + lane]);
    float* hp = hend + (size_t)chain * NCH * NSTC + lane;
    const float* sp = sumd + (size_t)chain * NCH;
    float h = 0.f;
    for (int c = 0; c < NCH; ++c) {
        float he = hp[(size_t)c * NSTC];
        float sd = sp[c];
        hp[(size_t)c * NSTC] = h;
        h = fmaf(__expf(An * sd), h, he);
    }
}

// ---------- 4c. scan phase 3: LDS-staged re-scan, emit y ----------
__global__ __launch_bounds__(256) void scan3_k(const float* __restrict__ dts,
                                               const float2* __restrict__ bc2,
                                               const float* __restrict__ alog,
                                               const float* __restrict__ dtw,
                                               const float* __restrict__ dtb,
                                               const float* __restrict__ xconv,
                                               const float* __restrict__ xconvT,
                                               const float* __restrict__ hpre,
                                               float* __restrict__ ys) {
    __shared__ float sdt[LC * DTRC];
    __shared__ float swr[DT * DTRC];
    __shared__ float sbias[DT];
    __shared__ float sdl[DT * LCP];
    __shared__ float sdx[DT * LCP];
    __shared__ float sy[DT * LC];
    __shared__ float2 sbc[LC * NSTC];
    int blk = blockIdx.x;
    int c = blk % NCH;
    int dtile = (blk / NCH) % NDT;
    int bk = blk / (NCH * NDT);
    int k = bk & 3, b = bk >> 2;
    int l0 = c * LC;
    int tid = threadIdx.x;
    const float* dsrc = dts + ((size_t)bk * LL + l0) * DTRC;
    for (int f = tid; f < LC * DTRC; f += 256) sdt[f] = dsrc[f];
    if (tid < DT * DTRC) swr[tid] = dtw[((size_t)k * DINC + dtile * DT) * DTRC + tid];
    if (tid < DT) sbias[tid] = dtb[k * DINC + dtile * DT + tid];
    const float2* bsrc = bc2 + ((size_t)bk * LL + l0) * NSTC;
    for (int f = tid; f < LC * NSTC; f += 256) sbc[f] = bsrc[f];
    bool rev = (k >= 2);
    for (int f = tid; f < DT * LC; f += 256) {
        int d_loc = f >> 6, s = f & 63;
        size_t bd = ((size_t)b * DINC + dtile * DT + d_loc) * LL;
        const float* xs = (k & 1) ? (xconvT + bd) : (xconv + bd);
        sdx[d_loc * LCP + s] = xs[rev ? (LL - 1 - (l0 + s)) : (l0 + s)];
    }
    __syncthreads();
    for (int f = tid; f < DT * LC; f += 256) {
        int d_loc = f >> 6, s = f & 63;
        float acc = sbias[d_loc];
#pragma unroll
        for (int r = 0; r < DTRC; ++r) acc = fmaf(swr[d_loc * DTRC + r], sdt[s * DTRC + r], acc);
        float dv = softplusf(acc);
        sdl[d_loc * LCP + s] = dv;
        sdx[d_loc * LCP + s] *= dv;
    }
    __syncthreads();
    int g = tid >> 4, lane = tid & 15;
    int d = dtile * DT + g;
    float An = -__expf(alog[((size_t)(k * DINC + d)) * NSTC + lane]);
    int chain = bk * DINC + d;
    const float* pl = &sdl[g * LCP];
    const float* px = &sdx[g * LCP];
    float h = hpre[((size_t)chain * NCH + c) * NSTC + lane];
#pragma unroll 8
    for (int s = 0; s < LC; ++s) {
        float2 bcv = sbc[s * NSTC + lane];
        h = fmaf(__expf(pl[s] * An), h, px[s] * bcv.x);
        float p = h * bcv.y;
        p += __shfl_xor(p, 1, 16);
        p += __shfl_xor(p, 2, 16);
        p += __shfl_xor(p, 4, 16);
        p += __shfl_xor(p, 8, 16);
        if (lane == 0) sy[g * LC + s] = p;
    }
    __syncthreads();
    float* yo = ys + ((size_t)bk * DINC + dtile * DT) * LL + l0;
    {
        int d_loc = tid >> 4, s4 = tid & 15;
        *(float4*)&yo[(size_t)d_loc * LL + s4 * 4] = *(const float4*)&sy[d_loc * LC + s4 * 4];
    }
}

// ---------- 5. combine 4 directions (+ D*x) with in-LDS transpose ----------
__global__ __launch_bounds__(448) void combine_k(const float* __restrict__ ys,
                                                 const float* __restrict__ xconv,
                                                 const float* __restrict__ dsv,
                                                 float* __restrict__ yt) {
    __shared__ float T[56 * 57];
    int bd = blockIdx.x;
    int d = bd % DINC, b = bd / DINC;
    const float* y0 = ys + ((size_t)(b * KDIR + 0) * DINC + d) * LL;
    const float* y1 = ys + ((size_t)(b * KDIR + 1) * DINC + d) * LL;
    const float* y2 = ys + ((size_t)(b * KDIR + 2) * DINC + d) * LL;
    const float* y3 = ys + ((size_t)(b * KDIR + 3) * DINC + d) * LL;
    for (int l = threadIdx.x; l < LL; l += 448)
        T[(l % 56) * 57 + (l / 56)] = y1[l] + y3[LL - 1 - l];
    float sD = dsv[d] + dsv[DINC + d] + dsv[2 * DINC + d] + dsv[3 * DINC + d];
    size_t base = (size_t)bd * LL;
    __syncthreads();
    for (int pos = threadIdx.x; pos < LL; pos += 448) {
        float y = y0[pos] + y2[LL - 1 - pos] + T[(pos / 56) * 57 + (pos % 56)];
        yt[base + pos] = fmaf(xconv[base + pos], sD, y);
    }
}

// ---------- 6. fused out_norm*silu(z) + out_proj + residual ----------
__global__ __launch_bounds__(256) void gemm2_k(const float* __restrict__ yt,
                                               const float* __restrict__ g,
                                               const float* __restrict__ bt,
                                               const float* __restrict__ zs,
                                               const float* __restrict__ opw,
                                               const float* __restrict__ x,
                                               const float* __restrict__ sc1,
                                               float* __restrict__ vl) {
    __shared__ float xT[64 * 193];
    __shared__ float wT[96 * 52];
    __shared__ float mA[64], iA[64];
    int row0 = blockIdx.x * 64;
    int b = row0 / LL, pos0 = row0 % LL;
    for (int f = threadIdx.x; f < 192 * 16; f += 256) {
        int ch = f >> 4, po = (f & 15) * 4;
        float4 v = *(const float4*)&yt[((size_t)b * DINC + ch) * LL + pos0 + po];
        xT[(po + 0) * 193 + ch] = v.x; xT[(po + 1) * 193 + ch] = v.y;
        xT[(po + 2) * 193 + ch] = v.z; xT[(po + 3) * 193 + ch] = v.w;
    }
    __syncthreads();
    if (threadIdx.x < 64) {
        float s = 0.f, q = 0.f;
        const float* xr = &xT[threadIdx.x * 193];
        for (int c = 0; c < 192; ++c) { float v = xr[c]; s += v; q = fmaf(v, v, q); }
        float m = s * (1.f / 192.f);
        mA[threadIdx.x] = m;
        iA[threadIdx.x] = rsqrtf(q * (1.f / 192.f) - m * m + EPSF);
    }
    __syncthreads();
    for (int e = threadIdx.x; e < 64 * 192; e += 256) {
        int row = e / 192, col = e - row * 192;
        float v = xT[row * 193 + col];
        float z = zs[(size_t)row0 * DINC + e];
        xT[row * 193 + col] = ((v - mA[row]) * iA[row] * g[col] + bt[col]) * z;
    }
    int tc = threadIdx.x & 15, tr = threadIdx.x >> 4;
    float acc[4][6] = {};
    for (int kc = 0; kc < 4; ++kc) {
        __syncthreads();
        for (int f = threadIdx.x; f < 96 * 12; f += 256) {
            int r = f / 12, kq = (f % 12) * 4;
            *(float4*)&wT[r * 52 + kq] = *(const float4*)&opw[(size_t)r * DINC + kc * 48 + kq];
        }
        __syncthreads();
        for (int k = 0; k < 48; ++k) {
            float xv[4], wv[6];
#pragma unroll
            for (int i = 0; i < 4; ++i) xv[i] = xT[(4 * tr + i) * 193 + kc * 48 + k];
#pragma unroll
            for (int j = 0; j < 6; ++j) wv[j] = wT[(tc + 16 * j) * 52 + k];
#pragma unroll
            for (int i = 0; i < 4; ++i)
#pragma unroll
                for (int j = 0; j < 6; ++j) acc[i][j] = fmaf(xv[i], wv[j], acc[i][j]);
        }
    }
#pragma unroll
    for (int i = 0; i < 4; ++i) {
        int pos = pos0 + 4 * tr + i;
#pragma unroll
        for (int j = 0; j < 6; ++j) {
            int col = tc + 16 * j;
            float v = fmaf(sc1[col], x[((size_t)b * DIMC + col) * LL + pos], acc[i][j]);
            vl[(size_t)(row0 + 4 * tr + i) * DIMC + col] = v;
        }
    }
}

// ---------- 7. LN2 + conv1x1(96->24) + BN + ReLU ----------
__global__ __launch_bounds__(256) void ln2conv1_k(const float* __restrict__ vl,
                                                  const float* __restrict__ g,
                                                  const float* __restrict__ bt,
                                                  const float* __restrict__ w1,
                                                  const float* __restrict__ g1,
                                                  const float* __restrict__ b1,
                                                  const float* __restrict__ m1,
                                                  const float* __restrict__ v1,
                                                  float* __restrict__ h1) {
    __shared__ float row[4][96];
    int wv = threadIdx.x >> 6, lane = threadIdx.x & 63;
    int pix = blockIdx.x * 4 + wv;
    const float* vr = vl + (size_t)pix * DIMC;
    float a0 = vr[lane];
    float a1 = (lane < 32) ? vr[64 + lane] : 0.f;
    float s = a0 + a1, q = a0 * a0 + a1 * a1;
    for (int o = 32; o; o >>= 1) { s += __shfl_xor(s, o, 64); q += __shfl_xor(q, o, 64); }
    float m = s * (1.f / 96.f);
    float inv = rsqrtf(q * (1.f / 96.f) - m * m + EPSF);
    row[wv][lane] = (a0 - m) * inv * g[lane] + bt[lane];
    if (lane < 32) row[wv][64 + lane] = (a1 - m) * inv * g[64 + lane] + bt[64 + lane];
    __syncthreads();
    if (lane < 24) {
        const float* wr = w1 + lane * 96;
        float acc = 0.f;
#pragma unroll 8
        for (int c = 0; c < 96; ++c) acc = fmaf(row[wv][c], wr[c], acc);
        float bn = (acc - m1[lane]) * rsqrtf(v1[lane] + EPSF) * g1[lane] + b1[lane];
        int b = pix / LL, pos = pix % LL;
        h1[((size_t)b * 24 + lane) * LL + pos] = fmaxf(bn, 0.f);
    }
}

// ---------- 8. conv3x3 (24->24) + BN + ReLU ----------
__global__ __launch_bounds__(256) void conv2_k(const float* __restrict__ h1,
                                               const float* __restrict__ w2,
                                               const float* __restrict__ g2,
                                               const float* __restrict__ b2,
                                               const float* __restrict__ m2,
                                               const float* __restrict__ v2,
                                               float* __restrict__ h2) {
    int i = blockIdx.x * 256 + threadIdx.x;
    int pos = i % LL, mo = (i / LL) % 24, b = i / (LL * 24);
    int hh = pos / WWD, ww = pos % WWD;
    float acc = 0.f;
    for (int c = 0; c < 24; ++c) {
        const float* src = h1 + ((size_t)b * 24 + c) * LL;
        const float* wk = w2 + ((size_t)(mo * 24 + c)) * 9;
#pragma unroll
        for (int ky = 0; ky < 3; ++ky) {
            int y = hh + ky - 1;
            if ((unsigned)y >= HH) continue;
#pragma unroll
            for (int kx = 0; kx < 3; ++kx) {
                int xq = ww + kx - 1;
                if ((unsigned)xq >= WWD) continue;
                acc = fmaf(wk[ky * 3 + kx], src[y * WWD + xq], acc);
            }
        }
    }
    float bn = (acc - m2[mo]) * rsqrtf(v2[mo] + EPSF) * g2[mo] + b2[mo];
    h2[i] = fmaxf(bn, 0.f);
}

// ---------- 9. conv1x1 (24->96) + BN ----------
__global__ __launch_bounds__(256) void conv3_k(const float* __restrict__ h2,
                                               const float* __restrict__ w3,
                                               const float* __restrict__ g3,
                                               const float* __restrict__ b3,
                                               const float* __restrict__ m3,
                                               const float* __restrict__ v3,
                                               float* __restrict__ h3) {
    int i = blockIdx.x * 256 + threadIdx.x;
    int pos = i % LL, c = (i / LL) % DIMC, b = i / (LL * DIMC);
    const float* wr = w3 + c * 24;
    float acc = 0.f;
#pragma unroll
    for (int mo = 0; mo < 24; ++mo)
        acc = fmaf(wr[mo], h2[((size_t)b * 24 + mo) * LL + pos], acc);
    h3[i] = (acc - m3[c]) * rsqrtf(v3[c] + EPSF) * g3[c] + b3[c];
}

// ---------- 10. SE pool ----------
__global__ __launch_bounds__(256) void pool_k(const float* __restrict__ h3,
                                              float* __restrict__ pooled) {
    int bc = blockIdx.x;
    const float* p = h3 + (size_t)bc * LL;
    float s = 0.f;
    for (int i = threadIdx.x; i < LL; i += 256) s += p[i];
    for (int o = 32; o; o >>= 1) s += __shfl_xor(s, o, 64);
    __shared__ float wsum[4];
    if ((threadIdx.x & 63) == 0) wsum[threadIdx.x >> 6] = s;
    __syncthreads();
    if (threadIdx.x == 0) pooled[bc] = (wsum[0] + wsum[1] + wsum[2] + wsum[3]) * (1.f / 3136.f);
}

// ---------- 11. SE MLP ----------
__global__ __launch_bounds__(128) void semlp_k(const float* __restrict__ pooled,
                                               const float* __restrict__ sw1,
                                               const float* __restrict__ sw2,
                                               float* __restrict__ sew) {
    __shared__ float pl[2][96];
    __shared__ float hid[2][24];
    for (int i = threadIdx.x; i < 192; i += 128) pl[i / 96][i % 96] = pooled[i];
    __syncthreads();
    if (threadIdx.x < 48) {
        int b = threadIdx.x / 24, mo = threadIdx.x % 24;
        float acc = 0.f;
        for (int c = 0; c < 96; ++c) acc = fmaf(pl[b][c], sw1[mo * 96 + c], acc);
        hid[b][mo] = fmaxf(acc, 0.f);
    }
    __syncthreads();
    for (int i = threadIdx.x; i < 192; i += 128) {
        int b = i / 96, c = i % 96;
        float acc = 0.f;
        for (int mo = 0; mo < 24; ++mo) acc = fmaf(hid[b][mo], sw2[c * 24 + mo], acc);
        sew[i] = 1.f / (1.f + __expf(-acc));
    }
}

// ---------- 12. final ----------
__global__ __launch_bounds__(256) void final_k(const float* __restrict__ h3,
                                               const float* __restrict__ sew,
                                               const float* __restrict__ vl,
                                               const float* __restrict__ sc2,
                                               float* __restrict__ out) {
    int i = blockIdx.x * 256 + threadIdx.x;
    int pos = i % LL, c = (i / LL) % DIMC, b = i / (LL * DIMC);
    out[i] = fmaf(h3[i], sew[b * DIMC + c],
                  sc2[c] * vl[((size_t)b * LL + pos) * DIMC + c]);
}

extern "C" void kernel_launch(void* const* d_in, const int* in_sizes, int n_in,
                              void* d_out, int out_size, void* d_ws, size_t ws_size,
                              hipStream_t stream) {
    const float* x    = (const float*)d_in[0];
    const float* n1g  = (const float*)d_in[1];
    const float* n1b  = (const float*)d_in[2];
    const float* ipw  = (const float*)d_in[3];
    const float* cw   = (const float*)d_in[4];
    const float* cb   = (const float*)d_in[5];
    const float* xpw  = (const float*)d_in[6];
    const float* dtw  = (const float*)d_in[7];
    const float* dtb  = (const float*)d_in[8];
    const float* alog = (const float*)d_in[9];
    const float* dsv  = (const float*)d_in[10];
    const float* ong  = (const float*)d_in[11];
    const float* onb  = (const float*)d_in[12];
    const float* opw  = (const float*)d_in[13];
    const float* sc1  = (const float*)d_in[14];
    const float* n2g  = (const float*)d_in[15];
    const float* n2b  = (const float*)d_in[16];
    const float* w1   = (const float*)d_in[17];
    const float* g1   = (const float*)d_in[18];
    const float* b1   = (const float*)d_in[19];
    const float* m1   = (const float*)d_in[20];
    const float* v1   = (const float*)d_in[21];
    const float* w2   = (const float*)d_in[22];
    const float* g2   = (const float*)d_in[23];
    const float* b2   = (const float*)d_in[24];
    const float* m2   = (const float*)d_in[25];
    const float* v2   = (const float*)d_in[26];
    const float* w3   = (const float*)d_in[27];
    const float* g3   = (const float*)d_in[28];
    const float* b3   = (const float*)d_in[29];
    const float* m3   = (const float*)d_in[30];
    const float* v3   = (const float*)d_in[31];
    const float* sw1  = (const float*)d_in[32];
    const float* sw2  = (const float*)d_in[33];
    const float* sc2  = (const float*)d_in[34];
    float* ws = (float*)d_ws;
    float* out = (float*)d_out;

    gemm1_k<<<dim3(NPIX / 64, 4), 256, 0, stream>>>(x, n1g, n1b, ipw,
                                                    ws + OFF_XCRAW, ws + OFF_ZS);
    dwconvt_k<<<BB * DINC, 448, 0, stream>>>(ws + OFF_XCRAW, cw, cb,
                                             ws + OFF_XCONV, ws + OFF_XCONVT);
    gemmx_k<<<NPIX / 64, 256, 0, stream>>>(ws + OFF_XCONV, xpw, ws + OFF_DTS, ws + OFF_BC);

    scan1_k<<<BB * KDIR * NDT * NCH, 256, 0, stream>>>(
        ws + OFF_DTS, (const float2*)(ws + OFF_BC), alog, dtw, dtb,
        ws + OFF_XCONV, ws + OFF_XCONVT, ws + OFF_HEND, ws + OFF_SUMD);
    scan2_k<<<NCHAIN / 16, 256, 0, stream>>>(ws + OFF_HEND, ws + OFF_SUMD, alog);
    scan3_k<<<BB * KDIR * NDT * NCH, 256, 0, stream>>>(
        ws + OFF_DTS, (const float2*)(ws + OFF_BC), alog, dtw, dtb,
        ws + OFF_XCONV, ws + OFF_XCONVT, ws + OFF_HEND, ws + OFF_YS);

    combine_k<<<BB * DINC, 448, 0, stream>>>(ws + OFF_YS, ws + OFF_XCONV, dsv, ws + OFF_YT);
    gemm2_k<<<NPIX / 64, 256, 0, stream>>>(ws + OFF_YT, ong, onb, ws + OFF_ZS, opw, x, sc1,
                                           ws + OFF_VL);
    ln2conv1_k<<<NPIX / 4, 256, 0, stream>>>(ws + OFF_VL, n2g, n2b, w1, g1, b1, m1, v1,
                                             ws + OFF_H1);
    conv2_k<<<(BB * 24 * LL) / 256, 256, 0, stream>>>(ws + OFF_H1, w2, g2, b2, m2, v2,
                                                      ws + OFF_H2);
    conv3_k<<<(BB * DIMC * LL) / 256, 256, 0, stream>>>(ws + OFF_H2, w3, g3, b3, m3, v3,
                                                        ws + OFF_H3);
    pool_k<<<BB * DIMC, 256, 0, stream>>>(ws + OFF_H3, ws + OFF_POOL);
    semlp_k<<<1, 128, 0, stream>>>(ws + OFF_POOL, sw1, sw2, ws + OFF_SEW);
    final_k<<<(BB * DIMC * LL) / 256, 256, 0, stream>>>(ws + OFF_H3, ws + OFF_SEW, ws + OFF_VL,
                                                        sc2, out);
    (void)in_sizes; (void)n_in; (void)out_size; (void)ws_size;
}

// Round 8
// 252.651 us; speedup vs baseline: 2.2399x; 1.1447x over previous
//
#include <hip/hip_runtime.h>
#include <math.h>

#define DIMC 96
#define DINC 192
#define NSTC 16
#define DTRC 6
#define KDIR 4
#define BB   2
#define HH   56
#define WWD  56
#define LL   3136
#define NPIX (BB*LL)           // 6272
#define EPSF 1e-5f
#define NCH  49                // chunks per chain
#define LC   64                // chunk length
#define LCP  65                // padded stride
#define NCHAIN (BB*KDIR*DINC)  // 1536
#define NCOLS 152              // 4*38
#define DT   16                // d-chains per scan block
#define NDT  (DINC/DT)         // 12

// ---------- workspace layout (float offsets) ----------
#define OFF_XN     0u          // 602112  sumd during scan; H3 later
#define OFF_XCRAW  602112u     // 1204224 xc pre-conv NCHW; hend during scan; y_t after
#define OFF_ZS     1806336u    // 1204224 silu(z)
#define OFF_XCONV  3010560u    // 1204224 silu(conv(xc)) NCHW
#define OFF_DTS    4214784u    // 150528  dts (B,K,L,6)
#define OFF_BC     4365312u    // 802816  (B,K,L,16,{B,C})
#define OFF_XCONVT 5168128u    // 1204224 transposed xconv (dead after pass1)
#define OFF_CUMD   6372352u    // 4816896 cumΔ (chain,l) (dead after pass2)
#define OFF_YS     14801920u   // 4816896 ys (B,K,192,L)
#define OFF_HEND   OFF_XCRAW   // 1536*49*16 = 1204224 exactly
#define OFF_SUMD   OFF_XN      // 1536*49
#define OFF_YT     OFF_XCRAW
#define OFF_VL     OFF_XCONVT              // 602112 (xconvT dead after pass1)
#define OFF_H1     (OFF_XCONVT + 1300000u) // overlaps cumd; used after pass2 only
#define OFF_H2     (OFF_XCONVT + 1500000u)
#define OFF_H3     OFF_XN
#define OFF_POOL   (OFF_XCONVT + 1700000u)
#define OFF_SEW    (OFF_XCONVT + 1700448u)

__device__ __forceinline__ float siluf(float x) { return x / (1.f + __expf(-x)); }
__device__ __forceinline__ float softplusf(float x) {
    return fmaxf(x, 0.f) + __logf(1.f + __expf(-fabsf(x)));
}

#if __has_builtin(__builtin_amdgcn_update_dpp)
template <int CTRL>
__device__ __forceinline__ float dppadd(float v) {
    union { float f; int i; } a, r;
    a.f = v;
    r.i = __builtin_amdgcn_update_dpp(0, a.i, CTRL, 0xF, 0xF, false);
    return v + r.f;
}
// sum over 16-lane row into ALL lanes: quad_perm(1,0,3,2), quad_perm(2,3,0,1), row_ror:4, row_ror:8
__device__ __forceinline__ float rowsum16(float p) {
    p = dppadd<0xB1>(p);
    p = dppadd<0x4E>(p);
    p = dppadd<0x124>(p);
    p = dppadd<0x128>(p);
    return p;
}
#else
__device__ __forceinline__ float rowsum16(float p) {
    p += __shfl_xor(p, 1, 16);
    p += __shfl_xor(p, 2, 16);
    p += __shfl_xor(p, 4, 16);
    p += __shfl_xor(p, 8, 16);
    return p;
}
#endif

// ---------- 1. fused LN1 + in_proj GEMM. grid (98,4) x 256 ----------
__global__ __launch_bounds__(256) void gemm1_k(const float* __restrict__ x,
                                               const float* __restrict__ g,
                                               const float* __restrict__ bt,
                                               const float* __restrict__ W,
                                               float* __restrict__ xcr,
                                               float* __restrict__ zs) {
    __shared__ float xT[64 * 97];
    __shared__ float wT[96 * 100];
    __shared__ float mA[64], iA[64];
    int row0 = blockIdx.x * 64;
    int b = row0 / LL, pos0 = row0 % LL;
    int c0 = blockIdx.y * 96;
    for (int f = threadIdx.x; f < 96 * 16; f += 256) {
        int ch = f >> 4, po = (f & 15) * 4;
        float4 v = *(const float4*)&x[((size_t)b * DIMC + ch) * LL + pos0 + po];
        xT[(po + 0) * 97 + ch] = v.x; xT[(po + 1) * 97 + ch] = v.y;
        xT[(po + 2) * 97 + ch] = v.z; xT[(po + 3) * 97 + ch] = v.w;
    }
    for (int f = threadIdx.x; f < 96 * 24; f += 256) {
        int r = f / 24, kq = (f % 24) * 4;
        *(float4*)&wT[r * 100 + kq] = *(const float4*)&W[(size_t)(c0 + r) * DIMC + kq];
    }
    __syncthreads();
    if (threadIdx.x < 64) {
        float s = 0.f, q = 0.f;
        const float* xr = &xT[threadIdx.x * 97];
        for (int c = 0; c < 96; ++c) { float v = xr[c]; s += v; q = fmaf(v, v, q); }
        float m = s * (1.f / 96.f);
        mA[threadIdx.x] = m;
        iA[threadIdx.x] = rsqrtf(q * (1.f / 96.f) - m * m + EPSF);
    }
    __syncthreads();
    for (int e = threadIdx.x; e < 64 * 96; e += 256) {
        int row = e / 96, col = e - row * 96;
        float v = xT[row * 97 + col];
        xT[row * 97 + col] = (v - mA[row]) * iA[row] * g[col] + bt[col];
    }
    __syncthreads();
    int tc = threadIdx.x & 15, tr = threadIdx.x >> 4;
    float acc[4][6] = {};
    for (int k = 0; k < 96; ++k) {
        float xv[4], wv[6];
#pragma unroll
        for (int i = 0; i < 4; ++i) xv[i] = xT[(4 * tr + i) * 97 + k];
#pragma unroll
        for (int j = 0; j < 6; ++j) wv[j] = wT[(tc + 16 * j) * 100 + k];
#pragma unroll
        for (int i = 0; i < 4; ++i)
#pragma unroll
            for (int j = 0; j < 6; ++j) acc[i][j] = fmaf(xv[i], wv[j], acc[i][j]);
    }
    int pos = pos0 + 4 * tr;
    if (c0 < DINC) {
#pragma unroll
        for (int j = 0; j < 6; ++j) {
            int col = c0 + tc + 16 * j;
            float4 v = make_float4(acc[0][j], acc[1][j], acc[2][j], acc[3][j]);
            *(float4*)&xcr[((size_t)b * DINC + col) * LL + pos] = v;
        }
    } else {
#pragma unroll
        for (int i = 0; i < 4; ++i)
#pragma unroll
            for (int j = 0; j < 6; ++j) {
                int zc = c0 - DINC + tc + 16 * j;
                zs[(size_t)(row0 + 4 * tr + i) * DINC + zc] = siluf(acc[i][j]);
            }
    }
}

// ---------- 2. depthwise 3x3 conv + silu, emits xconv AND xconvT ----------
__global__ __launch_bounds__(448) void dwconvt_k(const float* __restrict__ xcr,
                                                 const float* __restrict__ cw,
                                                 const float* __restrict__ cb,
                                                 float* __restrict__ xconv,
                                                 float* __restrict__ xconvT) {
    __shared__ float P[56 * 57];
    __shared__ float T[56 * 57];
    int bd = blockIdx.x;
    int d = bd % DINC;
    size_t base = (size_t)bd * LL;
    for (int t = threadIdx.x; t < LL; t += 448)
        P[(t / 56) * 57 + (t % 56)] = xcr[base + t];
    float wk[9];
#pragma unroll
    for (int q = 0; q < 9; ++q) wk[q] = cw[d * 9 + q];
    float bias = cb[d];
    __syncthreads();
    for (int t = threadIdx.x; t < LL; t += 448) {
        int h = t / 56, w = t % 56;
        float acc = bias;
#pragma unroll
        for (int ky = 0; ky < 3; ++ky) {
            int y = h + ky - 1;
            if ((unsigned)y >= 56u) continue;
#pragma unroll
            for (int kx = 0; kx < 3; ++kx) {
                int xq = w + kx - 1;
                if ((unsigned)xq >= 56u) continue;
                acc = fmaf(wk[ky * 3 + kx], P[y * 57 + xq], acc);
            }
        }
        float v = siluf(acc);
        xconv[base + t] = v;
        T[w * 57 + h] = v;
    }
    __syncthreads();
    for (int t = threadIdx.x; t < LL; t += 448)
        xconvT[base + t] = T[(t / 56) * 57 + (t % 56)];
}

// ---------- 3. x_proj LDS-tiled GEMM -> scattered dts/bc. grid 98 x 256 ----------
__global__ __launch_bounds__(256) void gemmx_k(const float* __restrict__ xconv,
                                               const float* __restrict__ xpw,
                                               float* __restrict__ dts,
                                               float* __restrict__ bc) {
    __shared__ float xT[64 * 49];
    __shared__ float wT[NCOLS * 52];
    int row0 = blockIdx.x * 64;
    int b = row0 / LL, pos0 = row0 % LL;
    int tc = threadIdx.x & 15, tr = threadIdx.x >> 4;
    float acc[4][10] = {};
    for (int kc = 0; kc < 4; ++kc) {
        if (kc) __syncthreads();
        for (int f = threadIdx.x; f < 48 * 16; f += 256) {
            int dd = f >> 4, po = (f & 15) * 4;
            float4 v = *(const float4*)&xconv[((size_t)b * DINC + kc * 48 + dd) * LL + pos0 + po];
            xT[(po + 0) * 49 + dd] = v.x; xT[(po + 1) * 49 + dd] = v.y;
            xT[(po + 2) * 49 + dd] = v.z; xT[(po + 3) * 49 + dd] = v.w;
        }
        for (int f = threadIdx.x; f < NCOLS * 12; f += 256) {
            int r = f / 12, kq = (f % 12) * 4;
            *(float4*)&wT[r * 52 + kq] = *(const float4*)&xpw[(size_t)r * DINC + kc * 48 + kq];
        }
        __syncthreads();
        for (int k = 0; k < 48; ++k) {
            float xv[4], wv[10];
#pragma unroll
            for (int i = 0; i < 4; ++i) xv[i] = xT[(4 * tr + i) * 49 + k];
#pragma unroll
            for (int j = 0; j < 10; ++j) {
                int c = tc + 16 * j;
                wv[j] = (c < NCOLS) ? wT[c * 52 + k] : 0.f;
            }
#pragma unroll
            for (int i = 0; i < 4; ++i)
#pragma unroll
                for (int j = 0; j < 10; ++j) acc[i][j] = fmaf(xv[i], wv[j], acc[i][j]);
        }
    }
#pragma unroll
    for (int i = 0; i < 4; ++i) {
        int pos = pos0 + 4 * tr + i;
        int h = pos / 56, w = pos - 56 * h;
        int lt = w * 56 + h;
#pragma unroll
        for (int j = 0; j < 10; ++j) {
            int c = tc + 16 * j;
            if (c >= NCOLS) continue;
            int k = c / 38, idx = c - 38 * k;
            int l = (k == 0) ? pos : (k == 1) ? lt : (k == 2) ? (LL - 1 - pos) : (LL - 1 - lt);
            size_t rb = (size_t)(b * KDIR + k) * LL + l;
            float v = acc[i][j];
            if (idx < DTRC)    dts[rb * DTRC + idx] = v;
            else if (idx < 22) bc[(rb * NSTC + idx - 6) * 2] = v;
            else               bc[(rb * NSTC + idx - 22) * 2 + 1] = v;
        }
    }
}

// ---------- 4a. pass1: local scan per chunk -> y_local, cumΔ, h_end, ΣΔ ----------
// grid: BB*KDIR*NDT*NCH = 4704 x 256
__global__ __launch_bounds__(256) void pass1_k(const float* __restrict__ dts,
                                               const float2* __restrict__ bc2,
                                               const float* __restrict__ alog,
                                               const float* __restrict__ dtw,
                                               const float* __restrict__ dtb,
                                               const float* __restrict__ xconv,
                                               const float* __restrict__ xconvT,
                                               float* __restrict__ hend,
                                               float* __restrict__ sumd,
                                               float* __restrict__ ys,
                                               float* __restrict__ cumd) {
    __shared__ float sdt[LC * 7];        // pad 7: conflict-free strided read
    __shared__ float swr[DT * DTRC];
    __shared__ float sbias[DT];
    __shared__ float2 sddx[DT * LCP];    // (delta, delta*x)
    __shared__ float2 sbc[LC * NSTC];
    __shared__ float sy[DT * 68];
    __shared__ float scd[DT * 68];
    int blk = blockIdx.x;
    int c = blk % NCH;
    int dtile = (blk / NCH) % NDT;
    int bk = blk / (NCH * NDT);
    int k = bk & 3, b = bk >> 2;
    int l0 = c * LC;
    int tid = threadIdx.x;
    const float* dsrc = dts + ((size_t)bk * LL + l0) * DTRC;
    for (int f = tid; f < LC * DTRC; f += 256) sdt[(f / DTRC) * 7 + (f % DTRC)] = dsrc[f];
    if (tid < DT * DTRC) swr[tid] = dtw[((size_t)k * DINC + dtile * DT) * DTRC + tid];
    if (tid < DT) sbias[tid] = dtb[k * DINC + dtile * DT + tid];
    const float2* bsrc = bc2 + ((size_t)bk * LL + l0) * NSTC;
    for (int f = tid; f < LC * NSTC; f += 256) sbc[f] = bsrc[f];
    bool rev = (k >= 2);
    for (int f = tid; f < DT * LC; f += 256) {
        int d_loc = f >> 6, s = f & 63;
        size_t bd = ((size_t)b * DINC + dtile * DT + d_loc) * LL;
        const float* xs = (k & 1) ? (xconvT + bd) : (xconv + bd);
        sddx[d_loc * LCP + s].y = xs[rev ? (LL - 1 - (l0 + s)) : (l0 + s)];
    }
    __syncthreads();
    for (int f = tid; f < DT * LC; f += 256) {
        int d_loc = f >> 6, s = f & 63;
        float acc = sbias[d_loc];
#pragma unroll
        for (int r = 0; r < DTRC; ++r) acc = fmaf(swr[d_loc * DTRC + r], sdt[s * 7 + r], acc);
        float dv = softplusf(acc);
        float xv = sddx[d_loc * LCP + s].y;
        sddx[d_loc * LCP + s] = make_float2(dv, dv * xv);
    }
    __syncthreads();
    int g = tid >> 4, lane = tid & 15;
    int d = dtile * DT + g;
    float An = -__expf(alog[((size_t)(k * DINC + d)) * NSTC + lane]);
    const float2* pdx = &sddx[g * LCP];
    const float2* pbc = &sbc[lane];
    float h = 0.f, sd = 0.f;
#pragma unroll 8
    for (int s = 0; s < LC; ++s) {
        float2 ddx = pdx[s];
        float2 bcv = pbc[(size_t)s * NSTC];
        sd += ddx.x;
        h = fmaf(__expf(ddx.x * An), h, ddx.y * bcv.x);
        float p = rowsum16(h * bcv.y);
        if (lane == 0) { sy[g * 68 + s] = p; scd[g * 68 + s] = sd; }
    }
    int chain = bk * DINC + d;
    hend[((size_t)chain * NCH + c) * NSTC + lane] = h;
    if (lane == 0) sumd[(size_t)chain * NCH + c] = sd;
    __syncthreads();
    {
        int d_loc = tid >> 4, s4 = tid & 15;
        size_t row = ((size_t)bk * DINC + dtile * DT + d_loc) * LL + l0 + s4 * 4;
        *(float4*)&ys[row] = *(const float4*)&sy[d_loc * 68 + s4 * 4];
        *(float4*)&cumd[row] = *(const float4*)&scd[d_loc * 68 + s4 * 4];
    }
}

// ---------- 4b. scan2: sequential combine over chunks (hend -> hpre) ----------
__global__ __launch_bounds__(256) void scan2_k(float* __restrict__ hend,
                                               const float* __restrict__ sumd,
                                               const float* __restrict__ alog) {
    int chain = blockIdx.x * 16 + (threadIdx.x >> 4);
    int lane = threadIdx.x & 15;
    float An = -__expf(alog[(size_t)(chain % (KDIR * DINC)) * NSTC + lane]);
    float* hp = hend + (size_t)chain * NCH * NSTC + lane;
    const float* sp = sumd + (size_t)chain * NCH;
    float h = 0.f;
    for (int c = 0; c < NCH; ++c) {
        float he = hp[(size_t)c * NSTC];
        float sd = sp[c];
        hp[(size_t)c * NSTC] = h;
        h = fmaf(__expf(An * sd), h, he);
    }
}

// ---------- 4c. pass2: parallel correction y += sum_n C_n*exp(An*cumd)*hpre_n ----------
// grid: 4704 x 256
__global__ __launch_bounds__(256) void pass2_k(const float2* __restrict__ bc2,
                                               const float* __restrict__ alog,
                                               const float* __restrict__ hpre,
                                               const float* __restrict__ cumd,
                                               float* __restrict__ ys) {
    __shared__ float sA[DT * NSTC];
    __shared__ float sH[DT * NSTC];
    __shared__ float sCt[NSTC * 68];     // transposed C: [n][s]
    int blk = blockIdx.x;
    int c = blk % NCH;
    int dtile = (blk / NCH) % NDT;
    int bk = blk / (NCH * NDT);
    int k = bk & 3;
    int l0 = c * LC;
    int tid = threadIdx.x;
    {
        int d = tid >> 4, n = tid & 15;
        sA[tid] = -__expf(alog[((size_t)(k * DINC + dtile * DT + d)) * NSTC + n]);
        int chain = bk * DINC + dtile * DT + d;
        sH[tid] = hpre[((size_t)chain * NCH + c) * NSTC + n];
    }
    const float2* bsrc = bc2 + ((size_t)bk * LL + l0) * NSTC;
    for (int f = tid; f < LC * NSTC; f += 256) {
        int n = f & 15, s = f >> 4;
        sCt[n * 68 + s] = bsrc[f].y;
    }
    __syncthreads();
    int w = tid >> 6, s = tid & 63;
#pragma unroll
    for (int dd = 0; dd < 4; ++dd) {
        int d = w * 4 + dd;
        size_t row = ((size_t)bk * DINC + dtile * DT + d) * LL + l0 + s;
        float cd = cumd[row];
        float y = ys[row];
#pragma unroll
        for (int n = 0; n < NSTC; ++n) {
            float t = __expf(sA[d * NSTC + n] * cd);
            y = fmaf(sH[d * NSTC + n] * t, sCt[n * 68 + s], y);
        }
        ys[row] = y;
    }
}

// ---------- 5. combine 4 directions (+ D*x) with in-LDS transpose ----------
__global__ __launch_bounds__(448) void combine_k(const float* __restrict__ ys,
                                                 const float* __restrict__ xconv,
                                                 const float* __restrict__ dsv,
                                                 float* __restrict__ yt) {
    __shared__ float T[56 * 57];
    int bd = blockIdx.x;
    int d = bd % DINC, b = bd / DINC;
    const float* y0 = ys + ((size_t)(b * KDIR + 0) * DINC + d) * LL;
    const float* y1 = ys + ((size_t)(b * KDIR + 1) * DINC + d) * LL;
    const float* y2 = ys + ((size_t)(b * KDIR + 2) * DINC + d) * LL;
    const float* y3 = ys + ((size_t)(b * KDIR + 3) * DINC + d) * LL;
    for (int l = threadIdx.x; l < LL; l += 448)
        T[(l % 56) * 57 + (l / 56)] = y1[l] + y3[LL - 1 - l];
    float sD = dsv[d] + dsv[DINC + d] + dsv[2 * DINC + d] + dsv[3 * DINC + d];
    size_t base = (size_t)bd * LL;
    __syncthreads();
    for (int pos = threadIdx.x; pos < LL; pos += 448) {
        float y = y0[pos] + y2[LL - 1 - pos] + T[(pos / 56) * 57 + (pos % 56)];
        yt[base + pos] = fmaf(xconv[base + pos], sD, y);
    }
}

// ---------- 6. fused out_norm*silu(z) + out_proj + residual ----------
__global__ __launch_bounds__(256) void gemm2_k(const float* __restrict__ yt,
                                               const float* __restrict__ g,
                                               const float* __restrict__ bt,
                                               const float* __restrict__ zs,
                                               const float* __restrict__ opw,
                                               const float* __restrict__ x,
                                               const float* __restrict__ sc1,
                                               float* __restrict__ vl) {
    __shared__ float xT[64 * 193];
    __shared__ float wT[96 * 52];
    __shared__ float mA[64], iA[64];
    int row0 = blockIdx.x * 64;
    int b = row0 / LL, pos0 = row0 % LL;
    for (int f = threadIdx.x; f < 192 * 16; f += 256) {
        int ch = f >> 4, po = (f & 15) * 4;
        float4 v = *(const float4*)&yt[((size_t)b * DINC + ch) * LL + pos0 + po];
        xT[(po + 0) * 193 + ch] = v.x; xT[(po + 1) * 193 + ch] = v.y;
        xT[(po + 2) * 193 + ch] = v.z; xT[(po + 3) * 193 + ch] = v.w;
    }
    __syncthreads();
    if (threadIdx.x < 64) {
        float s = 0.f, q = 0.f;
        const float* xr = &xT[threadIdx.x * 193];
        for (int c = 0; c < 192; ++c) { float v = xr[c]; s += v; q = fmaf(v, v, q); }
        float m = s * (1.f / 192.f);
        mA[threadIdx.x] = m;
        iA[threadIdx.x] = rsqrtf(q * (1.f / 192.f) - m * m + EPSF);
    }
    __syncthreads();
    for (int e = threadIdx.x; e < 64 * 192; e += 256) {
        int row = e / 192, col = e - row * 192;
        float v = xT[row * 193 + col];
        float z = zs[(size_t)row0 * DINC + e];
        xT[row * 193 + col] = ((v - mA[row]) * iA[row] * g[col] + bt[col]) * z;
    }
    int tc = threadIdx.x & 15, tr = threadIdx.x >> 4;
    float acc[4][6] = {};
    for (int kc = 0; kc < 4; ++kc) {
        __syncthreads();
        for (int f = threadIdx.x; f < 96 * 12; f += 256) {
            int r = f / 12, kq = (f % 12) * 4;
            *(float4*)&wT[r * 52 + kq] = *(const float4*)&opw[(size_t)r * DINC + kc * 48 + kq];
        }
        __syncthreads();
        for (int k = 0; k < 48; ++k) {
            float xv[4], wv[6];
#pragma unroll
            for (int i = 0; i < 4; ++i) xv[i] = xT[(4 * tr + i) * 193 + kc * 48 + k];
#pragma unroll
            for (int j = 0; j < 6; ++j) wv[j] = wT[(tc + 16 * j) * 52 + k];
#pragma unroll
            for (int i = 0; i < 4; ++i)
#pragma unroll
                for (int j = 0; j < 6; ++j) acc[i][j] = fmaf(xv[i], wv[j], acc[i][j]);
        }
    }
#pragma unroll
    for (int i = 0; i < 4; ++i) {
        int pos = pos0 + 4 * tr + i;
#pragma unroll
        for (int j = 0; j < 6; ++j) {
            int col = tc + 16 * j;
            float v = fmaf(sc1[col], x[((size_t)b * DIMC + col) * LL + pos], acc[i][j]);
            vl[(size_t)(row0 + 4 * tr + i) * DIMC + col] = v;
        }
    }
}

// ---------- 7. LN2 + conv1x1(96->24) + BN + ReLU ----------
__global__ __launch_bounds__(256) void ln2conv1_k(const float* __restrict__ vl,
                                                  const float* __restrict__ g,
                                                  const float* __restrict__ bt,
                                                  const float* __restrict__ w1,
                                                  const float* __restrict__ g1,
                                                  const float* __restrict__ b1,
                                                  const float* __restrict__ m1,
                                                  const float* __restrict__ v1,
                                                  float* __restrict__ h1) {
    __shared__ float row[4][96];
    int wv = threadIdx.x >> 6, lane = threadIdx.x & 63;
    int pix = blockIdx.x * 4 + wv;
    const float* vr = vl + (size_t)pix * DIMC;
    float a0 = vr[lane];
    float a1 = (lane < 32) ? vr[64 + lane] : 0.f;
    float s = a0 + a1, q = a0 * a0 + a1 * a1;
    for (int o = 32; o; o >>= 1) { s += __shfl_xor(s, o, 64); q += __shfl_xor(q, o, 64); }
    float m = s * (1.f / 96.f);
    float inv = rsqrtf(q * (1.f / 96.f) - m * m + EPSF);
    row[wv][lane] = (a0 - m) * inv * g[lane] + bt[lane];
    if (lane < 32) row[wv][64 + lane] = (a1 - m) * inv * g[64 + lane] + bt[64 + lane];
    __syncthreads();
    if (lane < 24) {
        const float* wr = w1 + lane * 96;
        float acc = 0.f;
#pragma unroll 8
        for (int c = 0; c < 96; ++c) acc = fmaf(row[wv][c], wr[c], acc);
        float bn = (acc - m1[lane]) * rsqrtf(v1[lane] + EPSF) * g1[lane] + b1[lane];
        int b = pix / LL, pos = pix % LL;
        h1[((size_t)b * 24 + lane) * LL + pos] = fmaxf(bn, 0.f);
    }
}

// ---------- 8. conv3x3 (24->24) + BN + ReLU ----------
__global__ __launch_bounds__(256) void conv2_k(const float* __restrict__ h1,
                                               const float* __restrict__ w2,
                                               const float* __restrict__ g2,
                                               const float* __restrict__ b2,
                                               const float* __restrict__ m2,
                                               const float* __restrict__ v2,
                                               float* __restrict__ h2) {
    int i = blockIdx.x * 256 + threadIdx.x;
    int pos = i % LL, mo = (i / LL) % 24, b = i / (LL * 24);
    int hh = pos / WWD, ww = pos % WWD;
    float acc = 0.f;
    for (int c = 0; c < 24; ++c) {
        const float* src = h1 + ((size_t)b * 24 + c) * LL;
        const float* wk = w2 + ((size_t)(mo * 24 + c)) * 9;
#pragma unroll
        for (int ky = 0; ky < 3; ++ky) {
            int y = hh + ky - 1;
            if ((unsigned)y >= HH) continue;
#pragma unroll
            for (int kx = 0; kx < 3; ++kx) {
                int xq = ww + kx - 1;
                if ((unsigned)xq >= WWD) continue;
                acc = fmaf(wk[ky * 3 + kx], src[y * WWD + xq], acc);
            }
        }
    }
    float bn = (acc - m2[mo]) * rsqrtf(v2[mo] + EPSF) * g2[mo] + b2[mo];
    h2[i] = fmaxf(bn, 0.f);
}

// ---------- 9. conv1x1 (24->96) + BN ----------
__global__ __launch_bounds__(256) void conv3_k(const float* __restrict__ h2,
                                               const float* __restrict__ w3,
                                               const float* __restrict__ g3,
                                               const float* __restrict__ b3,
                                               const float* __restrict__ m3,
                                               const float* __restrict__ v3,
                                               float* __restrict__ h3) {
    int i = blockIdx.x * 256 + threadIdx.x;
    int pos = i % LL, c = (i / LL) % DIMC, b = i / (LL * DIMC);
    const float* wr = w3 + c * 24;
    float acc = 0.f;
#pragma unroll
    for (int mo = 0; mo < 24; ++mo)
        acc = fmaf(wr[mo], h2[((size_t)b * 24 + mo) * LL + pos], acc);
    h3[i] = (acc - m3[c]) * rsqrtf(v3[c] + EPSF) * g3[c] + b3[c];
}

// ---------- 10. SE pool ----------
__global__ __launch_bounds__(256) void pool_k(const float* __restrict__ h3,
                                              float* __restrict__ pooled) {
    int bc = blockIdx.x;
    const float* p = h3 + (size_t)bc * LL;
    float s = 0.f;
    for (int i = threadIdx.x; i < LL; i += 256) s += p[i];
    for (int o = 32; o; o >>= 1) s += __shfl_xor(s, o, 64);
    __shared__ float wsum[4];
    if ((threadIdx.x & 63) == 0) wsum[threadIdx.x >> 6] = s;
    __syncthreads();
    if (threadIdx.x == 0) pooled[bc] = (wsum[0] + wsum[1] + wsum[2] + wsum[3]) * (1.f / 3136.f);
}

// ---------- 11. SE MLP ----------
__global__ __launch_bounds__(128) void semlp_k(const float* __restrict__ pooled,
                                               const float* __restrict__ sw1,
                                               const float* __restrict__ sw2,
                                               float* __restrict__ sew) {
    __shared__ float pl[2][96];
    __shared__ float hid[2][24];
    for (int i = threadIdx.x; i < 192; i += 128) pl[i / 96][i % 96] = pooled[i];
    __syncthreads();
    if (threadIdx.x < 48) {
        int b = threadIdx.x / 24, mo = threadIdx.x % 24;
        float acc = 0.f;
        for (int c = 0; c < 96; ++c) acc = fmaf(pl[b][c], sw1[mo * 96 + c], acc);
        hid[b][mo] = fmaxf(acc, 0.f);
    }
    __syncthreads();
    for (int i = threadIdx.x; i < 192; i += 128) {
        int b = i / 96, c = i % 96;
        float acc = 0.f;
        for (int mo = 0; mo < 24; ++mo) acc = fmaf(hid[b][mo], sw2[c * 24 + mo], acc);
        sew[i] = 1.f / (1.f + __expf(-acc));
    }
}

// ---------- 12. final ----------
__global__ __launch_bounds__(256) void final_k(const float* __restrict__ h3,
                                               const float* __restrict__ sew,
                                               const float* __restrict__ vl,
                                               const float* __restrict__ sc2,
                                               float* __restrict__ out) {
    int i = blockIdx.x * 256 + threadIdx.x;
    int pos = i % LL, c = (i / LL) % DIMC, b = i / (LL * DIMC);
    out[i] = fmaf(h3[i], sew[b * DIMC + c],
                  sc2[c] * vl[((size_t)b * LL + pos) * DIMC + c]);
}

extern "C" void kernel_launch(void* const* d_in, const int* in_sizes, int n_in,
                              void* d_out, int out_size, void* d_ws, size_t ws_size,
                              hipStream_t stream) {
    const float* x    = (const float*)d_in[0];
    const float* n1g  = (const float*)d_in[1];
    const float* n1b  = (const float*)d_in[2];
    const float* ipw  = (const float*)d_in[3];
    const float* cw   = (const float*)d_in[4];
    const float* cb   = (const float*)d_in[5];
    const float* xpw  = (const float*)d_in[6];
    const float* dtw  = (const float*)d_in[7];
    const float* dtb  = (const float*)d_in[8];
    const float* alog = (const float*)d_in[9];
    const float* dsv  = (const float*)d_in[10];
    const float* ong  = (const float*)d_in[11];
    const float* onb  = (const float*)d_in[12];
    const float* opw  = (const float*)d_in[13];
    const float* sc1  = (const float*)d_in[14];
    const float* n2g  = (const float*)d_in[15];
    const float* n2b  = (const float*)d_in[16];
    const float* w1   = (const float*)d_in[17];
    const float* g1   = (const float*)d_in[18];
    const float* b1   = (const float*)d_in[19];
    const float* m1   = (const float*)d_in[20];
    const float* v1   = (const float*)d_in[21];
    const float* w2   = (const float*)d_in[22];
    const float* g2   = (const float*)d_in[23];
    const float* b2   = (const float*)d_in[24];
    const float* m2   = (const float*)d_in[25];
    const float* v2   = (const float*)d_in[26];
    const float* w3   = (const float*)d_in[27];
    const float* g3   = (const float*)d_in[28];
    const float* b3   = (const float*)d_in[29];
    const float* m3   = (const float*)d_in[30];
    const float* v3   = (const float*)d_in[31];
    const float* sw1  = (const float*)d_in[32];
    const float* sw2  = (const float*)d_in[33];
    const float* sc2  = (const float*)d_in[34];
    float* ws = (float*)d_ws;
    float* out = (float*)d_out;

    gemm1_k<<<dim3(NPIX / 64, 4), 256, 0, stream>>>(x, n1g, n1b, ipw,
                                                    ws + OFF_XCRAW, ws + OFF_ZS);
    dwconvt_k<<<BB * DINC, 448, 0, stream>>>(ws + OFF_XCRAW, cw, cb,
                                             ws + OFF_XCONV, ws + OFF_XCONVT);
    gemmx_k<<<NPIX / 64, 256, 0, stream>>>(ws + OFF_XCONV, xpw, ws + OFF_DTS, ws + OFF_BC);

    pass1_k<<<BB * KDIR * NDT * NCH, 256, 0, stream>>>(
        ws + OFF_DTS, (const float2*)(ws + OFF_BC), alog, dtw, dtb,
        ws + OFF_XCONV, ws + OFF_XCONVT, ws + OFF_HEND, ws + OFF_SUMD,
        ws + OFF_YS, ws + OFF_CUMD);
    scan2_k<<<NCHAIN / 16, 256, 0, stream>>>(ws + OFF_HEND, ws + OFF_SUMD, alog);
    pass2_k<<<BB * KDIR * NDT * NCH, 256, 0, stream>>>(
        (const float2*)(ws + OFF_BC), alog, ws + OFF_HEND, ws + OFF_CUMD, ws + OFF_YS);

    combine_k<<<BB * DINC, 448, 0, stream>>>(ws + OFF_YS, ws + OFF_XCONV, dsv, ws + OFF_YT);
    gemm2_k<<<NPIX / 64, 256, 0, stream>>>(ws + OFF_YT, ong, onb, ws + OFF_ZS, opw, x, sc1,
                                           ws + OFF_VL);
    ln2conv1_k<<<NPIX / 4, 256, 0, stream>>>(ws + OFF_VL, n2g, n2b, w1, g1, b1, m1, v1,
                                             ws + OFF_H1);
    conv2_k<<<(BB * 24 * LL) / 256, 256, 0, stream>>>(ws + OFF_H1, w2, g2, b2, m2, v2,
                                                      ws + OFF_H2);
    conv3_k<<<(BB * DIMC * LL) / 256, 256, 0, stream>>>(ws + OFF_H2, w3, g3, b3, m3, v3,
                                                        ws + OFF_H3);
    pool_k<<<BB * DIMC, 256, 0, stream>>>(ws + OFF_H3, ws + OFF_POOL);
    semlp_k<<<1, 128, 0, stream>>>(ws + OFF_POOL, sw1, sw2, ws + OFF_SEW);
    final_k<<<(BB * DIMC * LL) / 256, 256, 0, stream>>>(ws + OFF_H3, ws + OFF_SEW, ws + OFF_VL,
                                                        sc2, out);
    (void)in_sizes; (void)n_in; (void)out_size; (void)ws_size;
}